// Round 3
// baseline (703.838 us; speedup 1.0000x reference)
//
#include <hip/hip_runtime.h>
#include <hip/hip_bf16.h>

typedef short bf16x8 __attribute__((ext_vector_type(8)));   // 8 bf16 bit-patterns (4 VGPRs)
typedef float f32x4 __attribute__((ext_vector_type(4)));

__device__ __forceinline__ float bf2f(__hip_bfloat16 v) { return __bfloat162float(v); }

// ---------------- dtype detect: flag=1 -> tensors are f32, flag=0 -> bf16
__global__ void detect_kernel(const unsigned short* __restrict__ xu, int* __restrict__ flag) {
    if (blockIdx.x != 0 || threadIdx.x != 0) return;
    int good = 0;
    for (int i = 0; i < 128; i += 2) {           // even u16s: bf16 value vs f32 low-mantissa
        unsigned short u = xu[i];
        unsigned e = (u >> 7) & 0xFF;
        if (u == 0 || (e >= 110 && e <= 137)) good++;
    }
    *flag = (good < 32) ? 1 : 0;
}

__device__ __forceinline__ float loadAny(const void* p, size_t i, int isf32) {
    return isf32 ? ((const float*)p)[i] : bf2f(((const __hip_bfloat16*)p)[i]);
}

// ---------------- normalize a flat tensor to bf16
__global__ void ingest_kernel(const void* __restrict__ src, __hip_bfloat16* __restrict__ dst,
                              int n, const int* __restrict__ flag) {
    int isf32 = *flag;
    int t = blockIdx.x * blockDim.x + threadIdx.x;
    if (t >= n) return;
    dst[t] = __float2bfloat16(loadAny(src, t, isf32));
}

// ---------------- Wcat[n][k] = k<halfK ? Wl[n][k] : Wr[n][k-halfK], normalized to bf16
__global__ void buildwcat_kernel(const void* __restrict__ Wl, const void* __restrict__ Wr,
                                 __hip_bfloat16* __restrict__ Wcat, int kbits,
                                 const int* __restrict__ flag) {
    int isf32 = *flag;
    int t = blockIdx.x * blockDim.x + threadIdx.x;
    int total = 256 << kbits;
    if (t >= total) return;
    int halfK = 1 << (kbits - 1);
    int n = t >> kbits;
    int k = t & ((1 << kbits) - 1);
    float v = (k < halfK) ? loadAny(Wl, (size_t)n * halfK + k, isf32)
                          : loadAny(Wr, (size_t)n * halfK + (k - halfK), isf32);
    Wcat[t] = __float2bfloat16(v);
}

// ---------------- pack small tensors: sb = [b1l(0) b2l(256) Wh1(512) Wh2(1536) bh1(2304) bh2(2308)]
__global__ void smallpack_kernel(const void* b1l, const void* b2l, const void* Wh1,
                                 const void* Wh2, const void* bh1, const void* bh2,
                                 __hip_bfloat16* __restrict__ sb, const int* __restrict__ flag) {
    int isf32 = *flag;
    int t = blockIdx.x * blockDim.x + threadIdx.x;
    float v;
    if      (t < 256)  v = loadAny(b1l, t, isf32);
    else if (t < 512)  v = loadAny(b2l, t - 256, isf32);
    else if (t < 1536) v = loadAny(Wh1, t - 512, isf32);
    else if (t < 2304) v = loadAny(Wh2, t - 1536, isf32);
    else if (t < 2308) v = loadAny(bh1, t - 2304, isf32);
    else if (t < 2311) v = loadAny(bh2, t - 2308, isf32);
    else return;
    sb[t] = __float2bfloat16(v);
}

// ---------------- CSR build
__global__ void deg_kernel(const int* __restrict__ ei, int E, int* __restrict__ deg) {
    int t = blockIdx.x * blockDim.x + threadIdx.x;
    if (t >= E) return;
    atomicAdd(&deg[ei[E + t]], 1);
}

__global__ void scan_kernel(const int* __restrict__ deg, int* __restrict__ off, int N) {
    __shared__ int tmp[1024];
    __shared__ int carry_s;
    int tid = threadIdx.x;
    if (tid == 0) { carry_s = 0; off[0] = 0; }
    __syncthreads();
    for (int base = 0; base < N; base += 1024) {
        int i = base + tid;
        int v = (i < N) ? deg[i] : 0;
        tmp[tid] = v;
        __syncthreads();
        for (int d = 1; d < 1024; d <<= 1) {
            int t = (tid >= d) ? tmp[tid - d] : 0;
            __syncthreads();
            tmp[tid] += t;
            __syncthreads();
        }
        int c = carry_s;
        if (i < N) off[i + 1] = c + tmp[tid];
        __syncthreads();
        if (tid == 1023) carry_s = c + tmp[1023];
        __syncthreads();
    }
}

__global__ void fill_kernel(const int* __restrict__ ei, int E,
                            const int* __restrict__ off, int* __restrict__ cursor,
                            int* __restrict__ srcs) {
    int t = blockIdx.x * blockDim.x + threadIdx.x;
    if (t >= E) return;
    int dst = ei[E + t];
    int pos = off[dst] + atomicAdd(&cursor[dst], 1);
    srcs[pos] = ei[t];
}

// ---------------- gather-mean F=128 (bf16): one wave/node
__global__ void gather1_kernel(const __hip_bfloat16* __restrict__ x,
                               const int* __restrict__ off, const int* __restrict__ srcs,
                               __hip_bfloat16* __restrict__ agg, int N) {
    int wid  = (blockIdx.x * blockDim.x + threadIdx.x) >> 6;
    int lane = threadIdx.x & 63;
    if (wid >= N) return;
    int beg = off[wid], end = off[wid + 1];
    float a0 = 0.f, a1 = 0.f;
    const __hip_bfloat162* xb = (const __hip_bfloat162*)x;
    for (int e = beg; e < end; ++e) {
        int s = srcs[e];
        __hip_bfloat162 v = xb[(size_t)s * 64 + lane];
        a0 += bf2f(v.x); a1 += bf2f(v.y);
    }
    float inv = 1.0f / fmaxf((float)(end - beg), 1.0f);
    __hip_bfloat162 o;
    o.x = __float2bfloat16(a0 * inv);
    o.y = __float2bfloat16(a1 * inv);
    ((__hip_bfloat162*)agg)[(size_t)wid * 64 + lane] = o;
}

// ---------------- gather-mean F=256 (bf16): one wave/node
__global__ void gather2_kernel(const __hip_bfloat16* __restrict__ h,
                               const int* __restrict__ off, const int* __restrict__ srcs,
                               __hip_bfloat16* __restrict__ agg, int N) {
    int wid  = (blockIdx.x * blockDim.x + threadIdx.x) >> 6;
    int lane = threadIdx.x & 63;
    if (wid >= N) return;
    int beg = off[wid], end = off[wid + 1];
    float a0 = 0.f, a1 = 0.f, a2 = 0.f, a3 = 0.f;
    const __hip_bfloat162* hb = (const __hip_bfloat162*)h;
    for (int e = beg; e < end; ++e) {
        int s = srcs[e];
        __hip_bfloat162 v0 = hb[(size_t)s * 128 + 2 * lane];
        __hip_bfloat162 v1 = hb[(size_t)s * 128 + 2 * lane + 1];
        a0 += bf2f(v0.x); a1 += bf2f(v0.y);
        a2 += bf2f(v1.x); a3 += bf2f(v1.y);
    }
    float inv = 1.0f / fmaxf((float)(end - beg), 1.0f);
    __hip_bfloat162 o0, o1;
    o0.x = __float2bfloat16(a0 * inv); o0.y = __float2bfloat16(a1 * inv);
    o1.x = __float2bfloat16(a2 * inv); o1.y = __float2bfloat16(a3 * inv);
    __hip_bfloat162* ab = (__hip_bfloat162*)agg;
    ab[(size_t)wid * 128 + 2 * lane]     = o0;
    ab[(size_t)wid * 128 + 2 * lane + 1] = o1;
}

// ---------------- GEMM1 (all bf16): h1 = relu([A1|A2] @ W^T + bias)
template <int KA, int KB, bool RELU>
__global__ __launch_bounds__(256) void gemm_bf16(const __hip_bfloat16* __restrict__ A1,
                                                 const __hip_bfloat16* __restrict__ A2, int M,
                                                 const __hip_bfloat16* __restrict__ W,
                                                 const __hip_bfloat16* __restrict__ bias,
                                                 __hip_bfloat16* __restrict__ out) {
    constexpr int K = KA + KB;
    int wave = threadIdx.x >> 6;
    int lane = threadIdx.x & 63;
    int quad = lane >> 4;
    int l15  = lane & 15;
    int row0 = blockIdx.x * 64 + wave * 16;
    int m = row0 + l15;
    if (m > M - 1) m = M - 1;

    const short* a1 = (const short*)A1 + (size_t)m * KA + quad * 8;
    const short* a2 = (const short*)A2 + (size_t)m * KB + quad * 8;
    const short* wb = (const short*)W + (size_t)l15 * K + quad * 8;

    f32x4 acc[16];
#pragma unroll
    for (int i = 0; i < 16; i++) acc[i] = {0.f, 0.f, 0.f, 0.f};

#pragma unroll
    for (int kt = 0; kt < K; kt += 32) {
        bf16x8 a = (kt < KA) ? *(const bf16x8*)(a1 + kt)
                             : *(const bf16x8*)(a2 + (kt - KA));
#pragma unroll
        for (int nt = 0; nt < 16; nt++) {
            bf16x8 b = *(const bf16x8*)(wb + (size_t)(nt * 16) * K + kt);
            acc[nt] = __builtin_amdgcn_mfma_f32_16x16x32_bf16(a, b, acc[nt], 0, 0, 0);
        }
    }

#pragma unroll
    for (int nt = 0; nt < 16; nt++) {
        int col = nt * 16 + l15;
        float bv = bf2f(bias[col]);
#pragma unroll
        for (int r = 0; r < 4; r++) {
            int row = row0 + quad * 4 + r;
            if (row < M) {
                float v = acc[nt][r] + bv;
                if (RELU) v = fmaxf(v, 0.f);
                out[(size_t)row * 256 + col] = __float2bfloat16(v);
            }
        }
    }
}

// ---------------- GEMM2: h2 = [agg|h1] @ W^T + bias. Stores (a) flag-dtype h2 into
// d_out at element offset N*7, (b) bf16 h2 in-place into the h1 buffer (each wave
// reads exactly the 16 rows it writes, reads precede writes -> safe).
__global__ __launch_bounds__(256) void gemm2_kernel(const __hip_bfloat16* __restrict__ A1,
                                                    const __hip_bfloat16* A2, int M,
                                                    const __hip_bfloat16* __restrict__ W,
                                                    const __hip_bfloat16* __restrict__ bias,
                                                    __hip_bfloat16* h2b, void* dout,
                                                    const int* __restrict__ flag) {
    constexpr int KA = 256, K = 512;
    int isf32 = *flag;
    int wave = threadIdx.x >> 6;
    int lane = threadIdx.x & 63;
    int quad = lane >> 4;
    int l15  = lane & 15;
    int row0 = blockIdx.x * 64 + wave * 16;
    int m = row0 + l15;
    if (m > M - 1) m = M - 1;

    const short* a1 = (const short*)A1 + (size_t)m * KA + quad * 8;
    const short* a2 = (const short*)A2 + (size_t)m * KA + quad * 8;
    const short* wb = (const short*)W + (size_t)l15 * K + quad * 8;

    f32x4 acc[16];
#pragma unroll
    for (int i = 0; i < 16; i++) acc[i] = {0.f, 0.f, 0.f, 0.f};

#pragma unroll
    for (int kt = 0; kt < K; kt += 32) {
        bf16x8 a = (kt < KA) ? *(const bf16x8*)(a1 + kt)
                             : *(const bf16x8*)(a2 + (kt - KA));
#pragma unroll
        for (int nt = 0; nt < 16; nt++) {
            bf16x8 b = *(const bf16x8*)(wb + (size_t)(nt * 16) * K + kt);
            acc[nt] = __builtin_amdgcn_mfma_f32_16x16x32_bf16(a, b, acc[nt], 0, 0, 0);
        }
    }

    float* hf = (float*)dout + (size_t)M * 7;
    __hip_bfloat16* hb = (__hip_bfloat16*)dout + (size_t)M * 7;
#pragma unroll
    for (int nt = 0; nt < 16; nt++) {
        int col = nt * 16 + l15;
        float bv = bf2f(bias[col]);
#pragma unroll
        for (int r = 0; r < 4; r++) {
            int row = row0 + quad * 4 + r;
            if (row < M) {
                float v = acc[nt][r] + bv;
                size_t idx = (size_t)row * 256 + col;
                h2b[idx] = __float2bfloat16(v);
                if (isf32) hf[idx] = v;
                else       hb[idx] = __float2bfloat16(v);
            }
        }
    }
}

// ---------------- heads: out1[N,4] @ d_out+0, out2[N,3] @ d_out+N*4 (flag dtype)
__global__ void heads_kernel(const __hip_bfloat16* __restrict__ h2,
                             const __hip_bfloat16* __restrict__ sb,
                             void* dout, int N, const int* __restrict__ flag) {
    int isf32 = *flag;
    int node = (blockIdx.x * blockDim.x + threadIdx.x) >> 6;
    int lane = threadIdx.x & 63;
    if (node >= N) return;
    const __hip_bfloat162* hr = (const __hip_bfloat162*)(h2 + (size_t)node * 256);
    __hip_bfloat162 a = hr[2 * lane];
    __hip_bfloat162 b = hr[2 * lane + 1];
    float hv0 = bf2f(a.x), hv1 = bf2f(a.y), hv2 = bf2f(b.x), hv3 = bf2f(b.y);
#pragma unroll
    for (int r = 0; r < 7; r++) {
        const __hip_bfloat16* wrow = (r < 4) ? (sb + 512 + r * 256) : (sb + 1536 + (r - 4) * 256);
        const __hip_bfloat162* wr2 = (const __hip_bfloat162*)wrow;
        __hip_bfloat162 wa = wr2[2 * lane];
        __hip_bfloat162 wb = wr2[2 * lane + 1];
        float p = hv0 * bf2f(wa.x) + hv1 * bf2f(wa.y) + hv2 * bf2f(wb.x) + hv3 * bf2f(wb.y);
        for (int off = 32; off > 0; off >>= 1) p += __shfl_down(p, off, 64);
        if (lane == 0) {
            float bias = (r < 4) ? bf2f(sb[2304 + r]) : bf2f(sb[2308 + (r - 4)]);
            float v = p + bias;
            size_t idx = (r < 4) ? ((size_t)node * 4 + r)
                                 : ((size_t)N * 4 + (size_t)node * 3 + (r - 4));
            if (isf32) ((float*)dout)[idx] = v;
            else       ((__hip_bfloat16*)dout)[idx] = __float2bfloat16(v);
        }
    }
}

extern "C" void kernel_launch(void* const* d_in, const int* in_sizes, int n_in,
                              void* d_out, int out_size, void* d_ws, size_t ws_size,
                              hipStream_t stream) {
    const void* x   = d_in[0];
    const int*  ei  = (const int*)d_in[1];
    const void* W1l = d_in[2];
    const void* b1l = d_in[3];
    const void* W1r = d_in[4];
    const void* W2l = d_in[5];
    const void* b2l = d_in[6];
    const void* W2r = d_in[7];
    const void* Wh1 = d_in[8];
    const void* bh1 = d_in[9];
    const void* Wh2 = d_in[10];
    const void* bh2 = d_in[11];

    const int N = in_sizes[0] / 128;   // 50000
    const int E = in_sizes[1] / 2;     // 800000

    // workspace layout (bytes), total ~68.4 MB, 64B-aligned offsets
    char* ws = (char*)d_ws;
    int*            offp   = (int*)(ws + 0);                   // (N+1)*4
    int*            deg    = (int*)(ws + 262144);              // N*4
    int*            cursor = (int*)(ws + 524288);              // N*4
    int*            srcs   = (int*)(ws + 786432);              // E*4
    __hip_bfloat16* W1c    = (__hip_bfloat16*)(ws + 3986432);  // 256*256*2
    __hip_bfloat16* W2c    = (__hip_bfloat16*)(ws + 4117504);  // 256*512*2
    __hip_bfloat16* sb     = (__hip_bfloat16*)(ws + 4379648);  // 8KB
    __hip_bfloat16* xn     = (__hip_bfloat16*)(ws + 4387840);  // N*128*2
    __hip_bfloat16* h1     = (__hip_bfloat16*)(ws + 17187840); // N*256*2
    __hip_bfloat16* agg    = (__hip_bfloat16*)(ws + 42787840); // N*256*2
    int*            flag   = (int*)(ws + 68387840);

    hipMemsetAsync(ws + 262144, 0, 524288, stream);   // zero deg + cursor

    detect_kernel<<<1, 64, 0, stream>>>((const unsigned short*)x, flag);

    ingest_kernel<<<(N * 128 + 255) / 256, 256, 0, stream>>>(x, xn, N * 128, flag);
    buildwcat_kernel<<<(256 * 256 + 255) / 256, 256, 0, stream>>>(W1l, W1r, W1c, 8, flag);
    buildwcat_kernel<<<(256 * 512 + 255) / 256, 256, 0, stream>>>(W2l, W2r, W2c, 9, flag);
    smallpack_kernel<<<(2311 + 255) / 256, 256, 0, stream>>>(b1l, b2l, Wh1, Wh2, bh1, bh2, sb, flag);

    deg_kernel<<<(E + 255) / 256, 256, 0, stream>>>(ei, E, deg);
    scan_kernel<<<1, 1024, 0, stream>>>(deg, offp, N);
    fill_kernel<<<(E + 255) / 256, 256, 0, stream>>>(ei, E, offp, cursor, srcs);

    // layer 1 (bf16): h1 = relu([agg1 | xn] @ W1c^T + b1l)
    gather1_kernel<<<(N + 3) / 4, 256, 0, stream>>>(xn, offp, srcs, agg, N);
    gemm_bf16<128, 128, true><<<(N + 63) / 64, 256, 0, stream>>>(agg, xn, N, W1c, sb, h1);

    // layer 2: h2 -> d_out h-region (flag dtype) + bf16 in-place into h1
    gather2_kernel<<<(N + 3) / 4, 256, 0, stream>>>(h1, offp, srcs, agg, N);
    gemm2_kernel<<<(N + 63) / 64, 256, 0, stream>>>(agg, h1, N, W2c, sb + 256, h1, d_out, flag);

    // heads -> out1/out2 (flag dtype)
    heads_kernel<<<(N + 3) / 4, 256, 0, stream>>>(h1, sb, d_out, N, flag);
}

// Round 4
// 513.608 us; speedup vs baseline: 1.3704x; 1.3704x over previous
//
#include <hip/hip_runtime.h>
#include <hip/hip_bf16.h>

typedef short bf16x8 __attribute__((ext_vector_type(8)));   // 8 bf16 bit-patterns (4 VGPRs)
typedef float f32x4 __attribute__((ext_vector_type(4)));

__device__ __forceinline__ float bf2f(__hip_bfloat16 v) { return __bfloat162float(v); }

// ---------------- dtype detect: flag=1 -> tensors are f32, flag=0 -> bf16
__global__ void detect_kernel(const unsigned short* __restrict__ xu, int* __restrict__ flag) {
    if (blockIdx.x != 0 || threadIdx.x != 0) return;
    int good = 0;
    for (int i = 0; i < 128; i += 2) {
        unsigned short u = xu[i];
        unsigned e = (u >> 7) & 0xFF;
        if (u == 0 || (e >= 110 && e <= 137)) good++;
    }
    *flag = (good < 32) ? 1 : 0;
}

__device__ __forceinline__ float loadAny(const void* p, size_t i, int isf32) {
    return isf32 ? ((const float*)p)[i] : bf2f(((const __hip_bfloat16*)p)[i]);
}

// ---------------- normalize a flat tensor to bf16
__global__ void ingest_kernel(const void* __restrict__ src, __hip_bfloat16* __restrict__ dst,
                              int n, const int* __restrict__ flag) {
    int isf32 = *flag;
    int t = blockIdx.x * blockDim.x + threadIdx.x;
    if (t >= n) return;
    dst[t] = __float2bfloat16(loadAny(src, t, isf32));
}

// ---------------- Wcat[n][k] = k<halfK ? Wl[n][k] : Wr[n][k-halfK], normalized to bf16
__global__ void buildwcat_kernel(const void* __restrict__ Wl, const void* __restrict__ Wr,
                                 __hip_bfloat16* __restrict__ Wcat, int kbits,
                                 const int* __restrict__ flag) {
    int isf32 = *flag;
    int t = blockIdx.x * blockDim.x + threadIdx.x;
    int total = 256 << kbits;
    if (t >= total) return;
    int halfK = 1 << (kbits - 1);
    int n = t >> kbits;
    int k = t & ((1 << kbits) - 1);
    float v = (k < halfK) ? loadAny(Wl, (size_t)n * halfK + k, isf32)
                          : loadAny(Wr, (size_t)n * halfK + (k - halfK), isf32);
    Wcat[t] = __float2bfloat16(v);
}

// ---------------- pack small tensors: sb = [b1l(0) b2l(256) Wh1(512) Wh2(1536) bh1(2304) bh2(2308)]
__global__ void smallpack_kernel(const void* b1l, const void* b2l, const void* Wh1,
                                 const void* Wh2, const void* bh1, const void* bh2,
                                 __hip_bfloat16* __restrict__ sb, const int* __restrict__ flag) {
    int isf32 = *flag;
    int t = blockIdx.x * blockDim.x + threadIdx.x;
    float v;
    if      (t < 256)  v = loadAny(b1l, t, isf32);
    else if (t < 512)  v = loadAny(b2l, t - 256, isf32);
    else if (t < 1536) v = loadAny(Wh1, t - 512, isf32);
    else if (t < 2304) v = loadAny(Wh2, t - 1536, isf32);
    else if (t < 2308) v = loadAny(bh1, t - 2304, isf32);
    else if (t < 2311) v = loadAny(bh2, t - 2308, isf32);
    else return;
    sb[t] = __float2bfloat16(v);
}

// ---------------- CSR build
__global__ void deg_kernel(const int* __restrict__ ei, int E, int* __restrict__ deg) {
    int t = blockIdx.x * blockDim.x + threadIdx.x;
    if (t >= E) return;
    atomicAdd(&deg[ei[E + t]], 1);
}

// scanA: block b scans deg[b*1024 .. b*1024+1023] -> off[i+1] (within-block inclusive), bsum[b]=total
__global__ __launch_bounds__(256) void scanA_kernel(const int* __restrict__ deg,
                                                    int* __restrict__ off,
                                                    int* __restrict__ bsum, int N) {
    __shared__ int ts[256];
    int t = threadIdx.x;
    int base = blockIdx.x * 1024 + t * 4;
    int v0 = (base + 0 < N) ? deg[base + 0] : 0;
    int v1 = (base + 1 < N) ? deg[base + 1] : 0;
    int v2 = (base + 2 < N) ? deg[base + 2] : 0;
    int v3 = (base + 3 < N) ? deg[base + 3] : 0;
    int i0 = v0, i1 = i0 + v1, i2 = i1 + v2, i3 = i2 + v3;
    ts[t] = i3;
    __syncthreads();
    for (int d = 1; d < 256; d <<= 1) {
        int x = (t >= d) ? ts[t - d] : 0;
        __syncthreads();
        ts[t] += x;
        __syncthreads();
    }
    int excl = (t > 0) ? ts[t - 1] : 0;
    if (base + 0 < N) off[base + 1] = excl + i0;
    if (base + 1 < N) off[base + 2] = excl + i1;
    if (base + 2 < N) off[base + 3] = excl + i2;
    if (base + 3 < N) off[base + 4] = excl + i3;
    if (t == 255) bsum[blockIdx.x] = ts[255];
}

// scanB: single block; bsum[b] <- exclusive prefix of block totals (nb <= 1024)
__global__ __launch_bounds__(1024) void scanB_kernel(int* __restrict__ bsum, int nb) {
    __shared__ int ts[1024];
    int t = threadIdx.x;
    ts[t] = (t < nb) ? bsum[t] : 0;
    __syncthreads();
    for (int d = 1; d < 1024; d <<= 1) {
        int x = (t >= d) ? ts[t - d] : 0;
        __syncthreads();
        ts[t] += x;
        __syncthreads();
    }
    if (t < nb) bsum[t] = (t > 0) ? ts[t - 1] : 0;
}

// addC: off[i+1] += bsum[i>>10]; off[0] = 0
__global__ void addC_kernel(int* __restrict__ off, const int* __restrict__ bsum, int N) {
    int i = blockIdx.x * blockDim.x + threadIdx.x;
    if (i == 0) off[0] = 0;
    if (i < N) off[i + 1] += bsum[i >> 10];
}

__global__ void fill_kernel(const int* __restrict__ ei, int E,
                            const int* __restrict__ off, int* __restrict__ cursor,
                            int* __restrict__ srcs) {
    int t = blockIdx.x * blockDim.x + threadIdx.x;
    if (t >= E) return;
    int dst = ei[E + t];
    int pos = off[dst] + atomicAdd(&cursor[dst], 1);
    srcs[pos] = ei[t];
}

// ---------------- gather-mean F=128 (bf16): one wave/node, 2-way edge unroll
__global__ void gather1_kernel(const __hip_bfloat16* __restrict__ x,
                               const int* __restrict__ off, const int* __restrict__ srcs,
                               __hip_bfloat16* __restrict__ agg, int N) {
    int wid  = (blockIdx.x * blockDim.x + threadIdx.x) >> 6;
    int lane = threadIdx.x & 63;
    if (wid >= N) return;
    int beg = off[wid], end = off[wid + 1];
    float a0 = 0.f, a1 = 0.f;
    const __hip_bfloat162* xb = (const __hip_bfloat162*)x;
    int e = beg;
    for (; e + 1 < end; e += 2) {
        int s0 = srcs[e], s1 = srcs[e + 1];
        __hip_bfloat162 u = xb[(size_t)s0 * 64 + lane];
        __hip_bfloat162 v = xb[(size_t)s1 * 64 + lane];
        a0 += bf2f(u.x) + bf2f(v.x);
        a1 += bf2f(u.y) + bf2f(v.y);
    }
    if (e < end) {
        int s = srcs[e];
        __hip_bfloat162 u = xb[(size_t)s * 64 + lane];
        a0 += bf2f(u.x); a1 += bf2f(u.y);
    }
    float inv = 1.0f / fmaxf((float)(end - beg), 1.0f);
    __hip_bfloat162 o;
    o.x = __float2bfloat16(a0 * inv);
    o.y = __float2bfloat16(a1 * inv);
    ((__hip_bfloat162*)agg)[(size_t)wid * 64 + lane] = o;
}

// ---------------- gather-mean F=256 (bf16): one wave/node, 8B loads, 2-way unroll
__global__ void gather2_kernel(const __hip_bfloat16* __restrict__ h,
                               const int* __restrict__ off, const int* __restrict__ srcs,
                               __hip_bfloat16* __restrict__ agg, int N) {
    int wid  = (blockIdx.x * blockDim.x + threadIdx.x) >> 6;
    int lane = threadIdx.x & 63;
    if (wid >= N) return;
    int beg = off[wid], end = off[wid + 1];
    float a0 = 0.f, a1 = 0.f, a2 = 0.f, a3 = 0.f;
    const __hip_bfloat162* hb = (const __hip_bfloat162*)h;   // row = 128 pairs
    int e = beg;
    for (; e + 1 < end; e += 2) {
        int s0 = srcs[e], s1 = srcs[e + 1];
        __hip_bfloat162 u0 = hb[(size_t)s0 * 128 + 2 * lane];
        __hip_bfloat162 u1 = hb[(size_t)s0 * 128 + 2 * lane + 1];
        __hip_bfloat162 w0 = hb[(size_t)s1 * 128 + 2 * lane];
        __hip_bfloat162 w1 = hb[(size_t)s1 * 128 + 2 * lane + 1];
        a0 += bf2f(u0.x) + bf2f(w0.x);
        a1 += bf2f(u0.y) + bf2f(w0.y);
        a2 += bf2f(u1.x) + bf2f(w1.x);
        a3 += bf2f(u1.y) + bf2f(w1.y);
    }
    if (e < end) {
        int s = srcs[e];
        __hip_bfloat162 u0 = hb[(size_t)s * 128 + 2 * lane];
        __hip_bfloat162 u1 = hb[(size_t)s * 128 + 2 * lane + 1];
        a0 += bf2f(u0.x); a1 += bf2f(u0.y);
        a2 += bf2f(u1.x); a3 += bf2f(u1.y);
    }
    float inv = 1.0f / fmaxf((float)(end - beg), 1.0f);
    __hip_bfloat162 o0, o1;
    o0.x = __float2bfloat16(a0 * inv); o0.y = __float2bfloat16(a1 * inv);
    o1.x = __float2bfloat16(a2 * inv); o1.y = __float2bfloat16(a3 * inv);
    __hip_bfloat162* ab = (__hip_bfloat162*)agg;
    ab[(size_t)wid * 128 + 2 * lane]     = o0;
    ab[(size_t)wid * 128 + 2 * lane + 1] = o1;
}

// ---------------- GEMM tile: out[M,256] = [A1|A2][M,KA+KB] @ W[256,K]^T + bias
// 2 waves/block; wave computes 32 rows x 256 cols (2 row-tiles share each B-frag).
// TOOUT=false: bf16 store to outb. TOOUT=true: flag-dtype store to dout at elem offset M*7.
template <int KA, int KB, bool RELU, bool TOOUT>
__global__ __launch_bounds__(128) void gemm_tile(const __hip_bfloat16* __restrict__ A1,
                                                 const __hip_bfloat16* __restrict__ A2, int M,
                                                 const __hip_bfloat16* __restrict__ W,
                                                 const __hip_bfloat16* __restrict__ bias,
                                                 __hip_bfloat16* __restrict__ outb,
                                                 void* __restrict__ dout,
                                                 const int* __restrict__ flag) {
    constexpr int K = KA + KB;
    int wave = threadIdx.x >> 6;
    int lane = threadIdx.x & 63;
    int quad = lane >> 4;
    int l15  = lane & 15;
    int row0 = blockIdx.x * 64 + wave * 32;
    int m0 = min(row0 + l15, M - 1);
    int m1 = min(row0 + 16 + l15, M - 1);

    const short* a1p0 = (const short*)A1 + (size_t)m0 * KA + quad * 8;
    const short* a1p1 = (const short*)A1 + (size_t)m1 * KA + quad * 8;
    const short* a2p0 = (const short*)A2 + (size_t)m0 * KB + quad * 8;
    const short* a2p1 = (const short*)A2 + (size_t)m1 * KB + quad * 8;
    const short* wp   = (const short*)W + (size_t)l15 * K + quad * 8;

    f32x4 acc[2][16];
#pragma unroll
    for (int rt = 0; rt < 2; rt++)
#pragma unroll
        for (int nt = 0; nt < 16; nt++) acc[rt][nt] = {0.f, 0.f, 0.f, 0.f};

    for (int kt = 0; kt < KA; kt += 32) {
        bf16x8 a0 = *(const bf16x8*)(a1p0 + kt);
        bf16x8 a1 = *(const bf16x8*)(a1p1 + kt);
#pragma unroll
        for (int nt = 0; nt < 16; nt++) {
            bf16x8 b = *(const bf16x8*)(wp + (size_t)(nt * 16) * K + kt);
            acc[0][nt] = __builtin_amdgcn_mfma_f32_16x16x32_bf16(a0, b, acc[0][nt], 0, 0, 0);
            acc[1][nt] = __builtin_amdgcn_mfma_f32_16x16x32_bf16(a1, b, acc[1][nt], 0, 0, 0);
        }
    }
    for (int kt = 0; kt < KB; kt += 32) {
        bf16x8 a0 = *(const bf16x8*)(a2p0 + kt);
        bf16x8 a1 = *(const bf16x8*)(a2p1 + kt);
#pragma unroll
        for (int nt = 0; nt < 16; nt++) {
            bf16x8 b = *(const bf16x8*)(wp + (size_t)(nt * 16) * K + (KA + kt));
            acc[0][nt] = __builtin_amdgcn_mfma_f32_16x16x32_bf16(a0, b, acc[0][nt], 0, 0, 0);
            acc[1][nt] = __builtin_amdgcn_mfma_f32_16x16x32_bf16(a1, b, acc[1][nt], 0, 0, 0);
        }
    }

    int isf32 = TOOUT ? *flag : 0;
    float* hf = TOOUT ? ((float*)dout + (size_t)M * 7) : nullptr;
    __hip_bfloat16* hb = TOOUT ? ((__hip_bfloat16*)dout + (size_t)M * 7) : outb;

#pragma unroll
    for (int rt = 0; rt < 2; rt++) {
#pragma unroll
        for (int nt = 0; nt < 16; nt++) {
            int col = nt * 16 + l15;
            float bv = bf2f(bias[col]);
#pragma unroll
            for (int r = 0; r < 4; r++) {
                int row = row0 + rt * 16 + quad * 4 + r;
                if (row < M) {
                    float v = acc[rt][nt][r] + bv;
                    if (RELU) v = fmaxf(v, 0.f);
                    size_t idx = (size_t)row * 256 + col;
                    if (TOOUT && isf32) hf[idx] = v;
                    else                hb[idx] = __float2bfloat16(v);
                }
            }
        }
    }
}

// ---------------- heads: out1[N,4] @ d_out+0, out2[N,3] @ d_out+N*4; reads h2 from
// d_out h-region (elem offset N*7) in flag dtype.
__global__ void heads_kernel(const __hip_bfloat16* __restrict__ sb,
                             void* dout, int N, const int* __restrict__ flag) {
    int isf32 = *flag;
    int node = (blockIdx.x * blockDim.x + threadIdx.x) >> 6;
    int lane = threadIdx.x & 63;
    if (node >= N) return;
    float hv0, hv1, hv2, hv3;
    if (isf32) {
        const float4* hp = (const float4*)((const float*)dout + (size_t)N * 7);
        float4 v = hp[(size_t)node * 64 + lane];
        hv0 = v.x; hv1 = v.y; hv2 = v.z; hv3 = v.w;
    } else {
        const __hip_bfloat162* hp = (const __hip_bfloat162*)((const __hip_bfloat16*)dout + (size_t)N * 7);
        __hip_bfloat162 a = hp[(size_t)node * 128 + 2 * lane];
        __hip_bfloat162 b = hp[(size_t)node * 128 + 2 * lane + 1];
        hv0 = bf2f(a.x); hv1 = bf2f(a.y); hv2 = bf2f(b.x); hv3 = bf2f(b.y);
    }
#pragma unroll
    for (int r = 0; r < 7; r++) {
        const __hip_bfloat16* wrow = (r < 4) ? (sb + 512 + r * 256) : (sb + 1536 + (r - 4) * 256);
        const __hip_bfloat162* wr2 = (const __hip_bfloat162*)wrow;
        __hip_bfloat162 wa = wr2[2 * lane];
        __hip_bfloat162 wb = wr2[2 * lane + 1];
        float p = hv0 * bf2f(wa.x) + hv1 * bf2f(wa.y) + hv2 * bf2f(wb.x) + hv3 * bf2f(wb.y);
        for (int off = 32; off > 0; off >>= 1) p += __shfl_down(p, off, 64);
        if (lane == 0) {
            float bias = (r < 4) ? bf2f(sb[2304 + r]) : bf2f(sb[2308 + (r - 4)]);
            float v = p + bias;
            size_t idx = (r < 4) ? ((size_t)node * 4 + r)
                                 : ((size_t)N * 4 + (size_t)node * 3 + (r - 4));
            if (isf32) ((float*)dout)[idx] = v;
            else       ((__hip_bfloat16*)dout)[idx] = __float2bfloat16(v);
        }
    }
}

extern "C" void kernel_launch(void* const* d_in, const int* in_sizes, int n_in,
                              void* d_out, int out_size, void* d_ws, size_t ws_size,
                              hipStream_t stream) {
    const void* x   = d_in[0];
    const int*  ei  = (const int*)d_in[1];
    const void* W1l = d_in[2];
    const void* b1l = d_in[3];
    const void* W1r = d_in[4];
    const void* W2l = d_in[5];
    const void* b2l = d_in[6];
    const void* W2r = d_in[7];
    const void* Wh1 = d_in[8];
    const void* bh1 = d_in[9];
    const void* Wh2 = d_in[10];
    const void* bh2 = d_in[11];

    const int N = in_sizes[0] / 128;   // 50000
    const int E = in_sizes[1] / 2;     // 800000
    const int NB = (N + 1023) / 1024;  // scan blocks (49)

    // workspace layout (bytes), total ~68.4 MB, 64B-aligned
    char* ws = (char*)d_ws;
    int*            offp   = (int*)(ws + 0);                   // (N+1)*4
    int*            deg    = (int*)(ws + 262144);              // N*4
    int*            cursor = (int*)(ws + 524288);              // N*4
    int*            bsum   = (int*)(ws + 724992);              // NB*4 (inside memset range)
    int*            srcs   = (int*)(ws + 786432);              // E*4
    __hip_bfloat16* W1c    = (__hip_bfloat16*)(ws + 3986432);  // 256*256*2
    __hip_bfloat16* W2c    = (__hip_bfloat16*)(ws + 4117504);  // 256*512*2
    __hip_bfloat16* sb     = (__hip_bfloat16*)(ws + 4379648);  // 8KB
    __hip_bfloat16* xn     = (__hip_bfloat16*)(ws + 4387840);  // N*128*2
    __hip_bfloat16* h1     = (__hip_bfloat16*)(ws + 17187840); // N*256*2
    __hip_bfloat16* agg    = (__hip_bfloat16*)(ws + 42787840); // N*256*2
    int*            flag   = (int*)(ws + 68387840);

    hipMemsetAsync(ws + 262144, 0, 524288, stream);   // zero deg + cursor + bsum

    detect_kernel<<<1, 64, 0, stream>>>((const unsigned short*)x, flag);

    ingest_kernel<<<(N * 128 + 255) / 256, 256, 0, stream>>>(x, xn, N * 128, flag);
    buildwcat_kernel<<<(256 * 256 + 255) / 256, 256, 0, stream>>>(W1l, W1r, W1c, 8, flag);
    buildwcat_kernel<<<(256 * 512 + 255) / 256, 256, 0, stream>>>(W2l, W2r, W2c, 9, flag);
    smallpack_kernel<<<(2311 + 255) / 256, 256, 0, stream>>>(b1l, b2l, Wh1, Wh2, bh1, bh2, sb, flag);

    // CSR build (hierarchical scan)
    deg_kernel<<<(E + 255) / 256, 256, 0, stream>>>(ei, E, deg);
    scanA_kernel<<<NB, 256, 0, stream>>>(deg, offp, bsum, N);
    scanB_kernel<<<1, 1024, 0, stream>>>(bsum, NB);
    addC_kernel<<<(N + 255) / 256, 256, 0, stream>>>(offp, bsum, N);
    fill_kernel<<<(E + 255) / 256, 256, 0, stream>>>(ei, E, offp, cursor, srcs);

    // layer 1 (bf16): h1 = relu([agg1 | xn] @ W1c^T + b1l)
    gather1_kernel<<<(N + 3) / 4, 256, 0, stream>>>(xn, offp, srcs, agg, N);
    gemm_tile<128, 128, true, false><<<(N + 63) / 64, 128, 0, stream>>>(
        agg, xn, N, W1c, sb, h1, nullptr, flag);

    // layer 2: h2 -> d_out h-region (flag dtype)
    gather2_kernel<<<(N + 3) / 4, 256, 0, stream>>>(h1, offp, srcs, agg, N);
    gemm_tile<256, 256, false, true><<<(N + 63) / 64, 128, 0, stream>>>(
        agg, h1, N, W2c, sb + 256, nullptr, d_out, flag);

    // heads -> out1/out2 (flag dtype), h2 read from d_out
    heads_kernel<<<(N + 3) / 4, 256, 0, stream>>>(sb, d_out, N, flag);
}

// Round 5
// 433.802 us; speedup vs baseline: 1.6225x; 1.1840x over previous
//
#include <hip/hip_runtime.h>
#include <hip/hip_bf16.h>

typedef short bf16x8 __attribute__((ext_vector_type(8)));   // 8 bf16 bit-patterns (4 VGPRs)
typedef float f32x4 __attribute__((ext_vector_type(4)));

__device__ __forceinline__ float bf2f(__hip_bfloat16 v) { return __bfloat162float(v); }

// ---------------- dtype detect: flag=1 -> tensors are f32, flag=0 -> bf16
__global__ void detect_kernel(const unsigned short* __restrict__ xu, int* __restrict__ flag) {
    if (blockIdx.x != 0 || threadIdx.x != 0) return;
    int good = 0;
    for (int i = 0; i < 128; i += 2) {
        unsigned short u = xu[i];
        unsigned e = (u >> 7) & 0xFF;
        if (u == 0 || (e >= 110 && e <= 137)) good++;
    }
    *flag = (good < 32) ? 1 : 0;
}

__device__ __forceinline__ float loadAny(const void* p, size_t i, int isf32) {
    return isf32 ? ((const float*)p)[i] : bf2f(((const __hip_bfloat16*)p)[i]);
}

// ---------------- normalize a flat tensor to bf16
__global__ void ingest_kernel(const void* __restrict__ src, __hip_bfloat16* __restrict__ dst,
                              int n, const int* __restrict__ flag) {
    int isf32 = *flag;
    int t = blockIdx.x * blockDim.x + threadIdx.x;
    if (t >= n) return;
    dst[t] = __float2bfloat16(loadAny(src, t, isf32));
}

// ---------------- Wcat[n][k] = k<halfK ? Wl[n][k] : Wr[n][k-halfK], normalized to bf16
__global__ void buildwcat_kernel(const void* __restrict__ Wl, const void* __restrict__ Wr,
                                 __hip_bfloat16* __restrict__ Wcat, int kbits,
                                 const int* __restrict__ flag) {
    int isf32 = *flag;
    int t = blockIdx.x * blockDim.x + threadIdx.x;
    int total = 256 << kbits;
    if (t >= total) return;
    int halfK = 1 << (kbits - 1);
    int n = t >> kbits;
    int k = t & ((1 << kbits) - 1);
    float v = (k < halfK) ? loadAny(Wl, (size_t)n * halfK + k, isf32)
                          : loadAny(Wr, (size_t)n * halfK + (k - halfK), isf32);
    Wcat[t] = __float2bfloat16(v);
}

// ---------------- pack small tensors: sb = [b1l(0) b2l(256) Wh1(512) Wh2(1536) bh1(2304) bh2(2308)]
__global__ void smallpack_kernel(const void* b1l, const void* b2l, const void* Wh1,
                                 const void* Wh2, const void* bh1, const void* bh2,
                                 __hip_bfloat16* __restrict__ sb, const int* __restrict__ flag) {
    int isf32 = *flag;
    int t = blockIdx.x * blockDim.x + threadIdx.x;
    float v;
    if      (t < 256)  v = loadAny(b1l, t, isf32);
    else if (t < 512)  v = loadAny(b2l, t - 256, isf32);
    else if (t < 1536) v = loadAny(Wh1, t - 512, isf32);
    else if (t < 2304) v = loadAny(Wh2, t - 1536, isf32);
    else if (t < 2308) v = loadAny(bh1, t - 2304, isf32);
    else if (t < 2311) v = loadAny(bh2, t - 2308, isf32);
    else return;
    sb[t] = __float2bfloat16(v);
}

// ---------------- CSR build
__global__ void deg_kernel(const int* __restrict__ ei, int E, int* __restrict__ deg) {
    int t = blockIdx.x * blockDim.x + threadIdx.x;
    if (t >= E) return;
    atomicAdd(&deg[ei[E + t]], 1);
}

__global__ __launch_bounds__(256) void scanA_kernel(const int* __restrict__ deg,
                                                    int* __restrict__ off,
                                                    int* __restrict__ bsum, int N) {
    __shared__ int ts[256];
    int t = threadIdx.x;
    int base = blockIdx.x * 1024 + t * 4;
    int v0 = (base + 0 < N) ? deg[base + 0] : 0;
    int v1 = (base + 1 < N) ? deg[base + 1] : 0;
    int v2 = (base + 2 < N) ? deg[base + 2] : 0;
    int v3 = (base + 3 < N) ? deg[base + 3] : 0;
    int i0 = v0, i1 = i0 + v1, i2 = i1 + v2, i3 = i2 + v3;
    ts[t] = i3;
    __syncthreads();
    for (int d = 1; d < 256; d <<= 1) {
        int x = (t >= d) ? ts[t - d] : 0;
        __syncthreads();
        ts[t] += x;
        __syncthreads();
    }
    int excl = (t > 0) ? ts[t - 1] : 0;
    if (base + 0 < N) off[base + 1] = excl + i0;
    if (base + 1 < N) off[base + 2] = excl + i1;
    if (base + 2 < N) off[base + 3] = excl + i2;
    if (base + 3 < N) off[base + 4] = excl + i3;
    if (t == 255) bsum[blockIdx.x] = ts[255];
}

__global__ __launch_bounds__(1024) void scanB_kernel(int* __restrict__ bsum, int nb) {
    __shared__ int ts[1024];
    int t = threadIdx.x;
    ts[t] = (t < nb) ? bsum[t] : 0;
    __syncthreads();
    for (int d = 1; d < 1024; d <<= 1) {
        int x = (t >= d) ? ts[t - d] : 0;
        __syncthreads();
        ts[t] += x;
        __syncthreads();
    }
    if (t < nb) bsum[t] = (t > 0) ? ts[t - 1] : 0;
}

__global__ void addC_kernel(int* __restrict__ off, const int* __restrict__ bsum, int N) {
    int i = blockIdx.x * blockDim.x + threadIdx.x;
    if (i == 0) off[0] = 0;
    if (i < N) off[i + 1] += bsum[i >> 10];
}

__global__ void fill_kernel(const int* __restrict__ ei, int E,
                            const int* __restrict__ off, int* __restrict__ cursor,
                            int* __restrict__ srcs) {
    int t = blockIdx.x * blockDim.x + threadIdx.x;
    if (t >= E) return;
    int dst = ei[E + t];
    int pos = off[dst] + atomicAdd(&cursor[dst], 1);
    srcs[pos] = ei[t];
}

// ---------------- gather-mean F=128 (bf16): one wave/node, 4-way edge unroll
__global__ void gather1_kernel(const __hip_bfloat16* __restrict__ x,
                               const int* __restrict__ off, const int* __restrict__ srcs,
                               __hip_bfloat16* __restrict__ agg, int N) {
    int wid  = (blockIdx.x * blockDim.x + threadIdx.x) >> 6;
    int lane = threadIdx.x & 63;
    if (wid >= N) return;
    int beg = off[wid], end = off[wid + 1];
    float a0 = 0.f, a1 = 0.f;
    const __hip_bfloat162* xb = (const __hip_bfloat162*)x;
    int e = beg;
    for (; e + 3 < end; e += 4) {
        int s0 = srcs[e], s1 = srcs[e + 1], s2 = srcs[e + 2], s3 = srcs[e + 3];
        __hip_bfloat162 u0 = xb[(size_t)s0 * 64 + lane];
        __hip_bfloat162 u1 = xb[(size_t)s1 * 64 + lane];
        __hip_bfloat162 u2 = xb[(size_t)s2 * 64 + lane];
        __hip_bfloat162 u3 = xb[(size_t)s3 * 64 + lane];
        a0 += bf2f(u0.x) + bf2f(u1.x) + bf2f(u2.x) + bf2f(u3.x);
        a1 += bf2f(u0.y) + bf2f(u1.y) + bf2f(u2.y) + bf2f(u3.y);
    }
    for (; e < end; e++) {
        int s = srcs[e];
        __hip_bfloat162 u = xb[(size_t)s * 64 + lane];
        a0 += bf2f(u.x); a1 += bf2f(u.y);
    }
    float inv = 1.0f / fmaxf((float)(end - beg), 1.0f);
    __hip_bfloat162 o;
    o.x = __float2bfloat16(a0 * inv);
    o.y = __float2bfloat16(a1 * inv);
    ((__hip_bfloat162*)agg)[(size_t)wid * 64 + lane] = o;
}

// ---------------- gather-mean F=256 (bf16): 128 threads/node (2 waves), 4-way unroll
__global__ void gather2_kernel(const __hip_bfloat16* __restrict__ h,
                               const int* __restrict__ off, const int* __restrict__ srcs,
                               __hip_bfloat16* __restrict__ agg, int N) {
    int gid  = blockIdx.x * blockDim.x + threadIdx.x;
    int node = gid >> 7;
    int t    = gid & 127;          // col-pair index, row = 128 pairs
    if (node >= N) return;
    int beg = off[node], end = off[node + 1];
    float a0 = 0.f, a1 = 0.f;
    const __hip_bfloat162* hb = (const __hip_bfloat162*)h;
    int e = beg;
    for (; e + 3 < end; e += 4) {
        int s0 = srcs[e], s1 = srcs[e + 1], s2 = srcs[e + 2], s3 = srcs[e + 3];
        __hip_bfloat162 u0 = hb[(size_t)s0 * 128 + t];
        __hip_bfloat162 u1 = hb[(size_t)s1 * 128 + t];
        __hip_bfloat162 u2 = hb[(size_t)s2 * 128 + t];
        __hip_bfloat162 u3 = hb[(size_t)s3 * 128 + t];
        a0 += bf2f(u0.x) + bf2f(u1.x) + bf2f(u2.x) + bf2f(u3.x);
        a1 += bf2f(u0.y) + bf2f(u1.y) + bf2f(u2.y) + bf2f(u3.y);
    }
    for (; e < end; e++) {
        int s = srcs[e];
        __hip_bfloat162 u = hb[(size_t)s * 128 + t];
        a0 += bf2f(u.x); a1 += bf2f(u.y);
    }
    float inv = 1.0f / fmaxf((float)(end - beg), 1.0f);
    __hip_bfloat162 o;
    o.x = __float2bfloat16(a0 * inv);
    o.y = __float2bfloat16(a1 * inv);
    ((__hip_bfloat162*)agg)[(size_t)node * 128 + t] = o;
}

// ---------------- LDS-staged GEMM: out[M,256] = [A1|A2][M,K] @ W[256,K]^T + bias
// Block: 256 thr (4 waves), 256 rows x 128 cols (col-half per blockIdx&1).
// W col-half staged in 64KB LDS in 256-k chunks; XOR-swizzled 16B chunks -> bank-uniform
// ds_read_b128 B-frags. Wave: 64 rows (acc[4][8]); per k-step 8 ds_read + 32 MFMA.
template <int K, int KA, bool RELU, bool TOOUT>
__global__ __launch_bounds__(256) void gemm_lds(const __hip_bfloat16* __restrict__ A1,
                                                const __hip_bfloat16* __restrict__ A2, int M,
                                                const __hip_bfloat16* __restrict__ W,
                                                const __hip_bfloat16* __restrict__ bias,
                                                __hip_bfloat16* __restrict__ outb,
                                                void* __restrict__ dout,
                                                const int* __restrict__ flag) {
    __shared__ short wlds[32768];                 // 64 KB: 128 cols x 256 k
    constexpr int KB = K - KA;
    constexpr int NCHUNK = K / 256;
    int tid  = threadIdx.x;
    int wave = tid >> 6, lane = tid & 63, quad = lane >> 4, l15 = lane & 15;
    int rowBlk = blockIdx.x >> 1, half = blockIdx.x & 1;
    int R0 = rowBlk * 256;
    int cbase = half * 128;

    int mrow[4];
#pragma unroll
    for (int rt = 0; rt < 4; rt++) mrow[rt] = min(R0 + wave * 64 + rt * 16 + l15, M - 1);

    f32x4 acc[4][8];
#pragma unroll
    for (int rt = 0; rt < 4; rt++)
#pragma unroll
        for (int nt = 0; nt < 8; nt++) acc[rt][nt] = {0.f, 0.f, 0.f, 0.f};

    for (int p = 0; p < NCHUNK; p++) {
        if (p > 0) __syncthreads();               // all waves done with previous chunk
        // stage W[cbase:cbase+128, p*256:p*256+256] -> LDS (swizzled)
#pragma unroll
        for (int i = 0; i < 16; i++) {
            int id = tid + i * 256;               // 0..4095
            int r = id >> 5;                      // col within half
            int c = id & 31;                      // 8-elem chunk
            bf16x8 v = *(const bf16x8*)((const short*)W + (size_t)(cbase + r) * K + p * 256 + c * 8);
            *(bf16x8*)&wlds[r * 256 + ((c ^ (r & 7)) * 8)] = v;
        }
        __syncthreads();
#pragma unroll
        for (int kt = 0; kt < 8; kt++) {
            int kglob = p * 256 + kt * 32;
            bf16x8 a[4];
#pragma unroll
            for (int rt = 0; rt < 4; rt++) {
                const short* ap = (kglob < KA)
                    ? (const short*)A1 + (size_t)mrow[rt] * KA + kglob + quad * 8
                    : (const short*)A2 + (size_t)mrow[rt] * KB + (kglob - KA) + quad * 8;
                a[rt] = *(const bf16x8*)ap;
            }
#pragma unroll
            for (int nt = 0; nt < 8; nt++) {
                int cp = (kt * 4 + quad) ^ (l15 & 7);
                bf16x8 b = *(const bf16x8*)&wlds[(nt * 16 + l15) * 256 + cp * 8];
#pragma unroll
                for (int rt = 0; rt < 4; rt++)
                    acc[rt][nt] = __builtin_amdgcn_mfma_f32_16x16x32_bf16(a[rt], b, acc[rt][nt], 0, 0, 0);
            }
        }
    }

    int isf32 = TOOUT ? *flag : 0;
    float* hf = TOOUT ? ((float*)dout + (size_t)M * 7) : nullptr;
    __hip_bfloat16* hb = TOOUT ? ((__hip_bfloat16*)dout + (size_t)M * 7) : outb;

#pragma unroll
    for (int rt = 0; rt < 4; rt++) {
#pragma unroll
        for (int nt = 0; nt < 8; nt++) {
            int col = cbase + nt * 16 + l15;
            float bv = bf2f(bias[col]);
#pragma unroll
            for (int r = 0; r < 4; r++) {
                int row = R0 + wave * 64 + rt * 16 + quad * 4 + r;
                if (row < M) {
                    float v = acc[rt][nt][r] + bv;
                    if (RELU) v = fmaxf(v, 0.f);
                    size_t idx = (size_t)row * 256 + col;
                    if (TOOUT && isf32) hf[idx] = v;
                    else                hb[idx] = __float2bfloat16(v);
                }
            }
        }
    }
}

// ---------------- heads: out1[N,4] @ d_out+0, out2[N,3] @ d_out+N*4; h2 from d_out (flag dtype)
__global__ void heads_kernel(const __hip_bfloat16* __restrict__ sb,
                             void* dout, int N, const int* __restrict__ flag) {
    int isf32 = *flag;
    int node = (blockIdx.x * blockDim.x + threadIdx.x) >> 6;
    int lane = threadIdx.x & 63;
    if (node >= N) return;
    float hv0, hv1, hv2, hv3;
    if (isf32) {
        const float4* hp = (const float4*)((const float*)dout + (size_t)N * 7);
        float4 v = hp[(size_t)node * 64 + lane];
        hv0 = v.x; hv1 = v.y; hv2 = v.z; hv3 = v.w;
    } else {
        const __hip_bfloat162* hp = (const __hip_bfloat162*)((const __hip_bfloat16*)dout + (size_t)N * 7);
        __hip_bfloat162 a = hp[(size_t)node * 128 + 2 * lane];
        __hip_bfloat162 b = hp[(size_t)node * 128 + 2 * lane + 1];
        hv0 = bf2f(a.x); hv1 = bf2f(a.y); hv2 = bf2f(b.x); hv3 = bf2f(b.y);
    }
#pragma unroll
    for (int r = 0; r < 7; r++) {
        const __hip_bfloat16* wrow = (r < 4) ? (sb + 512 + r * 256) : (sb + 1536 + (r - 4) * 256);
        const __hip_bfloat162* wr2 = (const __hip_bfloat162*)wrow;
        __hip_bfloat162 wa = wr2[2 * lane];
        __hip_bfloat162 wb = wr2[2 * lane + 1];
        float p = hv0 * bf2f(wa.x) + hv1 * bf2f(wa.y) + hv2 * bf2f(wb.x) + hv3 * bf2f(wb.y);
        for (int off = 32; off > 0; off >>= 1) p += __shfl_down(p, off, 64);
        if (lane == 0) {
            float bias = (r < 4) ? bf2f(sb[2304 + r]) : bf2f(sb[2308 + (r - 4)]);
            float v = p + bias;
            size_t idx = (r < 4) ? ((size_t)node * 4 + r)
                                 : ((size_t)N * 4 + (size_t)node * 3 + (r - 4));
            if (isf32) ((float*)dout)[idx] = v;
            else       ((__hip_bfloat16*)dout)[idx] = __float2bfloat16(v);
        }
    }
}

extern "C" void kernel_launch(void* const* d_in, const int* in_sizes, int n_in,
                              void* d_out, int out_size, void* d_ws, size_t ws_size,
                              hipStream_t stream) {
    const void* x   = d_in[0];
    const int*  ei  = (const int*)d_in[1];
    const void* W1l = d_in[2];
    const void* b1l = d_in[3];
    const void* W1r = d_in[4];
    const void* W2l = d_in[5];
    const void* b2l = d_in[6];
    const void* W2r = d_in[7];
    const void* Wh1 = d_in[8];
    const void* bh1 = d_in[9];
    const void* Wh2 = d_in[10];
    const void* bh2 = d_in[11];

    const int N = in_sizes[0] / 128;   // 50000
    const int E = in_sizes[1] / 2;     // 800000
    const int NB = (N + 1023) / 1024;  // scan blocks (49)

    // workspace layout (bytes), total ~68.4 MB, 64B-aligned
    char* ws = (char*)d_ws;
    int*            offp   = (int*)(ws + 0);                   // (N+1)*4
    int*            deg    = (int*)(ws + 262144);              // N*4
    int*            cursor = (int*)(ws + 524288);              // N*4
    int*            bsum   = (int*)(ws + 724992);              // NB*4 (inside memset range)
    int*            srcs   = (int*)(ws + 786432);              // E*4
    __hip_bfloat16* W1c    = (__hip_bfloat16*)(ws + 3986432);  // 256*256*2
    __hip_bfloat16* W2c    = (__hip_bfloat16*)(ws + 4117504);  // 256*512*2
    __hip_bfloat16* sb     = (__hip_bfloat16*)(ws + 4379648);  // 8KB
    __hip_bfloat16* xn     = (__hip_bfloat16*)(ws + 4387840);  // N*128*2
    __hip_bfloat16* h1     = (__hip_bfloat16*)(ws + 17187840); // N*256*2
    __hip_bfloat16* agg    = (__hip_bfloat16*)(ws + 42787840); // N*256*2
    int*            flag   = (int*)(ws + 68387840);

    hipMemsetAsync(ws + 262144, 0, 524288, stream);   // zero deg + cursor + bsum

    detect_kernel<<<1, 64, 0, stream>>>((const unsigned short*)x, flag);

    ingest_kernel<<<(N * 128 + 255) / 256, 256, 0, stream>>>(x, xn, N * 128, flag);
    buildwcat_kernel<<<(256 * 256 + 255) / 256, 256, 0, stream>>>(W1l, W1r, W1c, 8, flag);
    buildwcat_kernel<<<(256 * 512 + 255) / 256, 256, 0, stream>>>(W2l, W2r, W2c, 9, flag);
    smallpack_kernel<<<(2311 + 255) / 256, 256, 0, stream>>>(b1l, b2l, Wh1, Wh2, bh1, bh2, sb, flag);

    // CSR build (hierarchical scan)
    deg_kernel<<<(E + 255) / 256, 256, 0, stream>>>(ei, E, deg);
    scanA_kernel<<<NB, 256, 0, stream>>>(deg, offp, bsum, N);
    scanB_kernel<<<1, 1024, 0, stream>>>(bsum, NB);
    addC_kernel<<<(N + 255) / 256, 256, 0, stream>>>(offp, bsum, N);
    fill_kernel<<<(E + 255) / 256, 256, 0, stream>>>(ei, E, offp, cursor, srcs);

    const int rowBlks = (N + 255) / 256;   // 196

    // layer 1 (bf16): h1 = relu([agg1 | xn] @ W1c^T + b1l)
    gather1_kernel<<<(N + 3) / 4, 256, 0, stream>>>(xn, offp, srcs, agg, N);
    gemm_lds<256, 128, true, false><<<rowBlks * 2, 256, 0, stream>>>(
        agg, xn, N, W1c, sb, h1, nullptr, flag);

    // layer 2: h2 -> d_out h-region (flag dtype)
    gather2_kernel<<<(N * 128 + 255) / 256, 256, 0, stream>>>(h1, offp, srcs, agg, N);
    gemm_lds<512, 256, false, true><<<rowBlks * 2, 256, 0, stream>>>(
        agg, h1, N, W2c, sb + 256, nullptr, d_out, flag);

    // heads -> out1/out2 (flag dtype), h2 read from d_out
    heads_kernel<<<(N + 3) / 4, 256, 0, stream>>>(sb, d_out, N, flag);
}

// Round 6
// 407.577 us; speedup vs baseline: 1.7269x; 1.0643x over previous
//
#include <hip/hip_runtime.h>
#include <hip/hip_bf16.h>

typedef short bf16x8 __attribute__((ext_vector_type(8)));   // 8 bf16 bit-patterns (4 VGPRs)
typedef float f32x4 __attribute__((ext_vector_type(4)));

__device__ __forceinline__ float bf2f(__hip_bfloat16 v) { return __bfloat162float(v); }

// ---------------- dtype detect: flag=1 -> tensors are f32, flag=0 -> bf16
__global__ void detect_kernel(const unsigned short* __restrict__ xu, int* __restrict__ flag) {
    if (blockIdx.x != 0 || threadIdx.x != 0) return;
    int good = 0;
    for (int i = 0; i < 128; i += 2) {
        unsigned short u = xu[i];
        unsigned e = (u >> 7) & 0xFF;
        if (u == 0 || (e >= 110 && e <= 137)) good++;
    }
    *flag = (good < 32) ? 1 : 0;
}

__device__ __forceinline__ float loadAny(const void* p, size_t i, int isf32) {
    return isf32 ? ((const float*)p)[i] : bf2f(((const __hip_bfloat16*)p)[i]);
}

// ---------------- normalize x to bf16
__global__ void ingest_kernel(const void* __restrict__ src, __hip_bfloat16* __restrict__ dst,
                              int n, const int* __restrict__ flag) {
    int isf32 = *flag;
    int t = blockIdx.x * blockDim.x + threadIdx.x;
    if (t >= n) return;
    dst[t] = __float2bfloat16(loadAny(src, t, isf32));
}

// ---------------- weight prep (merged): W1c[65536] | W2c[131072] | sb[2311]
// W1c[n][k] = k<128 ? W1l[n][k] : W1r[n][k-128]   (256x256)
// W2c[n][k] = k<256 ? W2l[n][k] : W2r[n][k-256]   (256x512)
// sb = [b1l(0) b2l(256) Wh1(512) Wh2(1536) bh1(2304) bh2(2308)]
__global__ void prep_kernel(const void* W1l, const void* W1r, const void* W2l, const void* W2r,
                            const void* b1l, const void* b2l, const void* Wh1, const void* Wh2,
                            const void* bh1, const void* bh2,
                            __hip_bfloat16* __restrict__ W1c, __hip_bfloat16* __restrict__ W2c,
                            __hip_bfloat16* __restrict__ sb, const int* __restrict__ flag) {
    int isf32 = *flag;
    int t = blockIdx.x * blockDim.x + threadIdx.x;
    if (t < 65536) {
        int n = t >> 8, k = t & 255;
        float v = (k < 128) ? loadAny(W1l, n * 128 + k, isf32)
                            : loadAny(W1r, n * 128 + (k - 128), isf32);
        W1c[t] = __float2bfloat16(v);
        return;
    }
    int u = t - 65536;
    if (u < 131072) {
        int n = u >> 9, k = u & 511;
        float v = (k < 256) ? loadAny(W2l, n * 256 + k, isf32)
                            : loadAny(W2r, n * 256 + (k - 256), isf32);
        W2c[u] = __float2bfloat16(v);
        return;
    }
    int s = u - 131072;
    float v;
    if      (s < 256)  v = loadAny(b1l, s, isf32);
    else if (s < 512)  v = loadAny(b2l, s - 256, isf32);
    else if (s < 1536) v = loadAny(Wh1, s - 512, isf32);
    else if (s < 2304) v = loadAny(Wh2, s - 1536, isf32);
    else if (s < 2308) v = loadAny(bh1, s - 2304, isf32);
    else if (s < 2311) v = loadAny(bh2, s - 2308, isf32);
    else return;
    sb[s] = __float2bfloat16(v);
}

// ---------------- CSR build
__global__ void deg_kernel(const int* __restrict__ ei, int E, int* __restrict__ deg) {
    int t = blockIdx.x * blockDim.x + threadIdx.x;
    if (t >= E) return;
    atomicAdd(&deg[ei[E + t]], 1);
}

__global__ __launch_bounds__(256) void scanA_kernel(const int* __restrict__ deg,
                                                    int* __restrict__ off,
                                                    int* __restrict__ bsum, int N) {
    __shared__ int ts[256];
    int t = threadIdx.x;
    int base = blockIdx.x * 1024 + t * 4;
    int v0 = (base + 0 < N) ? deg[base + 0] : 0;
    int v1 = (base + 1 < N) ? deg[base + 1] : 0;
    int v2 = (base + 2 < N) ? deg[base + 2] : 0;
    int v3 = (base + 3 < N) ? deg[base + 3] : 0;
    int i0 = v0, i1 = i0 + v1, i2 = i1 + v2, i3 = i2 + v3;
    ts[t] = i3;
    __syncthreads();
    for (int d = 1; d < 256; d <<= 1) {
        int x = (t >= d) ? ts[t - d] : 0;
        __syncthreads();
        ts[t] += x;
        __syncthreads();
    }
    int excl = (t > 0) ? ts[t - 1] : 0;
    if (base + 0 < N) off[base + 1] = excl + i0;
    if (base + 1 < N) off[base + 2] = excl + i1;
    if (base + 2 < N) off[base + 3] = excl + i2;
    if (base + 3 < N) off[base + 4] = excl + i3;
    if (t == 255) bsum[blockIdx.x] = ts[255];
}

__global__ __launch_bounds__(1024) void scanB_kernel(int* __restrict__ bsum, int nb) {
    __shared__ int ts[1024];
    int t = threadIdx.x;
    ts[t] = (t < nb) ? bsum[t] : 0;
    __syncthreads();
    for (int d = 1; d < 1024; d <<= 1) {
        int x = (t >= d) ? ts[t - d] : 0;
        __syncthreads();
        ts[t] += x;
        __syncthreads();
    }
    if (t < nb) bsum[t] = (t > 0) ? ts[t - 1] : 0;
}

__global__ void addC_kernel(int* __restrict__ off, const int* __restrict__ bsum, int N) {
    int i = blockIdx.x * blockDim.x + threadIdx.x;
    if (i == 0) off[0] = 0;
    if (i < N) off[i + 1] += bsum[i >> 10];
}

__global__ void fill_kernel(const int* __restrict__ ei, int E,
                            const int* __restrict__ off, int* __restrict__ cursor,
                            int* __restrict__ srcs) {
    int t = blockIdx.x * blockDim.x + threadIdx.x;
    if (t >= E) return;
    int dst = ei[E + t];
    int pos = off[dst] + atomicAdd(&cursor[dst], 1);
    srcs[pos] = ei[t];
}

// ---------------- gather-mean F=128 (bf16): one wave/node, 4-way edge unroll
__global__ void gather1_kernel(const __hip_bfloat16* __restrict__ x,
                               const int* __restrict__ off, const int* __restrict__ srcs,
                               __hip_bfloat16* __restrict__ agg, int N) {
    int wid  = (blockIdx.x * blockDim.x + threadIdx.x) >> 6;
    int lane = threadIdx.x & 63;
    if (wid >= N) return;
    int beg = off[wid], end = off[wid + 1];
    float a0 = 0.f, a1 = 0.f;
    const __hip_bfloat162* xb = (const __hip_bfloat162*)x;
    int e = beg;
    for (; e + 3 < end; e += 4) {
        int s0 = srcs[e], s1 = srcs[e + 1], s2 = srcs[e + 2], s3 = srcs[e + 3];
        __hip_bfloat162 u0 = xb[(size_t)s0 * 64 + lane];
        __hip_bfloat162 u1 = xb[(size_t)s1 * 64 + lane];
        __hip_bfloat162 u2 = xb[(size_t)s2 * 64 + lane];
        __hip_bfloat162 u3 = xb[(size_t)s3 * 64 + lane];
        a0 += bf2f(u0.x) + bf2f(u1.x) + bf2f(u2.x) + bf2f(u3.x);
        a1 += bf2f(u0.y) + bf2f(u1.y) + bf2f(u2.y) + bf2f(u3.y);
    }
    for (; e < end; e++) {
        int s = srcs[e];
        __hip_bfloat162 u = xb[(size_t)s * 64 + lane];
        a0 += bf2f(u.x); a1 += bf2f(u.y);
    }
    float inv = 1.0f / fmaxf((float)(end - beg), 1.0f);
    __hip_bfloat162 o;
    o.x = __float2bfloat16(a0 * inv);
    o.y = __float2bfloat16(a1 * inv);
    ((__hip_bfloat162*)agg)[(size_t)wid * 64 + lane] = o;
}

// ---------------- gather-mean F=256 (bf16): 128 threads/node (2 waves), 4-way unroll
__global__ void gather2_kernel(const __hip_bfloat16* __restrict__ h,
                               const int* __restrict__ off, const int* __restrict__ srcs,
                               __hip_bfloat16* __restrict__ agg, int N) {
    int gid  = blockIdx.x * blockDim.x + threadIdx.x;
    int node = gid >> 7;
    int t    = gid & 127;
    if (node >= N) return;
    int beg = off[node], end = off[node + 1];
    float a0 = 0.f, a1 = 0.f;
    const __hip_bfloat162* hb = (const __hip_bfloat162*)h;
    int e = beg;
    for (; e + 3 < end; e += 4) {
        int s0 = srcs[e], s1 = srcs[e + 1], s2 = srcs[e + 2], s3 = srcs[e + 3];
        __hip_bfloat162 u0 = hb[(size_t)s0 * 128 + t];
        __hip_bfloat162 u1 = hb[(size_t)s1 * 128 + t];
        __hip_bfloat162 u2 = hb[(size_t)s2 * 128 + t];
        __hip_bfloat162 u3 = hb[(size_t)s3 * 128 + t];
        a0 += bf2f(u0.x) + bf2f(u1.x) + bf2f(u2.x) + bf2f(u3.x);
        a1 += bf2f(u0.y) + bf2f(u1.y) + bf2f(u2.y) + bf2f(u3.y);
    }
    for (; e < end; e++) {
        int s = srcs[e];
        __hip_bfloat162 u = hb[(size_t)s * 128 + t];
        a0 += bf2f(u.x); a1 += bf2f(u.y);
    }
    float inv = 1.0f / fmaxf((float)(end - beg), 1.0f);
    __hip_bfloat162 o;
    o.x = __float2bfloat16(a0 * inv);
    o.y = __float2bfloat16(a1 * inv);
    ((__hip_bfloat162*)agg)[(size_t)node * 128 + t] = o;
}

// ---------------- LDS-staged GEMM, software-pipelined.
// Block: 256 thr (4 waves), 256 rows x 128 cols (col-half = blockIdx&1).
// LDS: W chunk (128 cols x 256 k) stored in MFMA-FRAGMENT ORDER:
//   unit (kt*8+nt)*64 + lane, 16B per lane -> ds_read_b128 at base+lane*16 (0 conflicts).
// Pipeline: next-chunk W prefetched to regs during compute; next-kstep A frags
// prefetched to regs during MFMAs.
struct AFrag { bf16x8 v[4]; };

template <int K, int KA, bool RELU, bool TOOUT>
__global__ __launch_bounds__(256) void gemm_lds(const __hip_bfloat16* __restrict__ A1,
                                                const __hip_bfloat16* __restrict__ A2, int M,
                                                const __hip_bfloat16* __restrict__ W,
                                                const __hip_bfloat16* __restrict__ bias,
                                                __hip_bfloat16* __restrict__ outb,
                                                void* __restrict__ dout,
                                                const int* __restrict__ flag) {
    __shared__ short wlds[32768];                 // 64 KB: one 128x256 W chunk, frag-order
    constexpr int KB = K - KA;
    constexpr int NCHUNK = K / 256;
    int tid  = threadIdx.x;
    int wave = tid >> 6, lane = tid & 63, quad = lane >> 4, l15 = lane & 15;
    int rowBlk = blockIdx.x >> 1, half = blockIdx.x & 1;
    int R0 = rowBlk * 256;
    int cbase = half * 128;

    int mrow[4];
#pragma unroll
    for (int rt = 0; rt < 4; rt++) mrow[rt] = min(R0 + wave * 64 + rt * 16 + l15, M - 1);

    const short* Ws = (const short*)W;

    // W-chunk load (frag-order): thread covers units tid + i*256
    auto loadW = [&](int p, bf16x8* wreg) {
#pragma unroll
        for (int i = 0; i < 16; i++) {
            int unit = tid + i * 256;
            int ln = unit & 63, nt = (unit >> 6) & 7, kt = unit >> 9;
            int row = cbase + nt * 16 + (ln & 15);
            int kk  = p * 256 + kt * 32 + (ln >> 4) * 8;
            wreg[i] = *(const bf16x8*)(Ws + (size_t)row * K + kk);
        }
    };
    auto storeW = [&](const bf16x8* wreg) {
#pragma unroll
        for (int i = 0; i < 16; i++) {
            int unit = tid + i * 256;
            *(bf16x8*)&wlds[unit * 8] = wreg[i];
        }
    };
    auto loadA = [&](int kglob) {
        AFrag f;
#pragma unroll
        for (int rt = 0; rt < 4; rt++) {
            const short* ap = (kglob < KA)
                ? (const short*)A1 + (size_t)mrow[rt] * KA + kglob + quad * 8
                : (const short*)A2 + (size_t)mrow[rt] * KB + (kglob - KA) + quad * 8;
            f.v[rt] = *(const bf16x8*)ap;
        }
        return f;
    };

    f32x4 acc[4][8];
#pragma unroll
    for (int rt = 0; rt < 4; rt++)
#pragma unroll
        for (int nt = 0; nt < 8; nt++) acc[rt][nt] = {0.f, 0.f, 0.f, 0.f};

    bf16x8 wreg[16];
    loadW(0, wreg);
    storeW(wreg);
    __syncthreads();
    AFrag a_cur = loadA(0);

    for (int p = 0; p < NCHUNK; p++) {
        if (p + 1 < NCHUNK) loadW(p + 1, wreg);   // global->reg prefetch, no LDS hazard
#pragma unroll
        for (int kt = 0; kt < 8; kt++) {
            int kg = p * 256 + kt * 32;
            int kg_next = (kg + 32 < K) ? (kg + 32) : kg;   // clamp (last step: dummy reload)
            AFrag a_next = loadA(kg_next);
#pragma unroll
            for (int nt = 0; nt < 8; nt++) {
                bf16x8 b = *(const bf16x8*)&wlds[((kt * 8 + nt) * 64 + lane) * 8];
#pragma unroll
                for (int rt = 0; rt < 4; rt++)
                    acc[rt][nt] = __builtin_amdgcn_mfma_f32_16x16x32_bf16(a_cur.v[rt], b, acc[rt][nt], 0, 0, 0);
            }
            a_cur = a_next;
        }
        if (p + 1 < NCHUNK) {
            __syncthreads();          // all waves done reading chunk p
            storeW(wreg);
            __syncthreads();
        }
    }

    int isf32 = TOOUT ? *flag : 0;
    float* hf = TOOUT ? ((float*)dout + (size_t)M * 7) : nullptr;
    __hip_bfloat16* hb = TOOUT ? ((__hip_bfloat16*)dout + (size_t)M * 7) : outb;

#pragma unroll
    for (int rt = 0; rt < 4; rt++) {
#pragma unroll
        for (int nt = 0; nt < 8; nt++) {
            int col = cbase + nt * 16 + l15;
            float bv = bf2f(bias[col]);
#pragma unroll
            for (int r = 0; r < 4; r++) {
                int row = R0 + wave * 64 + rt * 16 + quad * 4 + r;
                if (row < M) {
                    float v = acc[rt][nt][r] + bv;
                    if (RELU) v = fmaxf(v, 0.f);
                    size_t idx = (size_t)row * 256 + col;
                    if (TOOUT && isf32) hf[idx] = v;
                    else                hb[idx] = __float2bfloat16(v);
                }
            }
        }
    }
}

// ---------------- heads: out1[N,4] @ d_out+0, out2[N,3] @ d_out+N*4; h2 from d_out (flag dtype)
__global__ void heads_kernel(const __hip_bfloat16* __restrict__ sb,
                             void* dout, int N, const int* __restrict__ flag) {
    int isf32 = *flag;
    int node = (blockIdx.x * blockDim.x + threadIdx.x) >> 6;
    int lane = threadIdx.x & 63;
    if (node >= N) return;
    float hv0, hv1, hv2, hv3;
    if (isf32) {
        const float4* hp = (const float4*)((const float*)dout + (size_t)N * 7);
        float4 v = hp[(size_t)node * 64 + lane];
        hv0 = v.x; hv1 = v.y; hv2 = v.z; hv3 = v.w;
    } else {
        const __hip_bfloat162* hp = (const __hip_bfloat162*)((const __hip_bfloat16*)dout + (size_t)N * 7);
        __hip_bfloat162 a = hp[(size_t)node * 128 + 2 * lane];
        __hip_bfloat162 b = hp[(size_t)node * 128 + 2 * lane + 1];
        hv0 = bf2f(a.x); hv1 = bf2f(a.y); hv2 = bf2f(b.x); hv3 = bf2f(b.y);
    }
#pragma unroll
    for (int r = 0; r < 7; r++) {
        const __hip_bfloat16* wrow = (r < 4) ? (sb + 512 + r * 256) : (sb + 1536 + (r - 4) * 256);
        const __hip_bfloat162* wr2 = (const __hip_bfloat162*)wrow;
        __hip_bfloat162 wa = wr2[2 * lane];
        __hip_bfloat162 wb = wr2[2 * lane + 1];
        float p = hv0 * bf2f(wa.x) + hv1 * bf2f(wa.y) + hv2 * bf2f(wb.x) + hv3 * bf2f(wb.y);
        for (int off = 32; off > 0; off >>= 1) p += __shfl_down(p, off, 64);
        if (lane == 0) {
            float bias = (r < 4) ? bf2f(sb[2304 + r]) : bf2f(sb[2308 + (r - 4)]);
            float v = p + bias;
            size_t idx = (r < 4) ? ((size_t)node * 4 + r)
                                 : ((size_t)N * 4 + (size_t)node * 3 + (r - 4));
            if (isf32) ((float*)dout)[idx] = v;
            else       ((__hip_bfloat16*)dout)[idx] = __float2bfloat16(v);
        }
    }
}

extern "C" void kernel_launch(void* const* d_in, const int* in_sizes, int n_in,
                              void* d_out, int out_size, void* d_ws, size_t ws_size,
                              hipStream_t stream) {
    const void* x   = d_in[0];
    const int*  ei  = (const int*)d_in[1];
    const void* W1l = d_in[2];
    const void* b1l = d_in[3];
    const void* W1r = d_in[4];
    const void* W2l = d_in[5];
    const void* b2l = d_in[6];
    const void* W2r = d_in[7];
    const void* Wh1 = d_in[8];
    const void* bh1 = d_in[9];
    const void* Wh2 = d_in[10];
    const void* bh2 = d_in[11];

    const int N = in_sizes[0] / 128;   // 50000
    const int E = in_sizes[1] / 2;     // 800000
    const int NB = (N + 1023) / 1024;  // scan blocks (49)

    // workspace layout (bytes), total ~68.4 MB, 64B-aligned
    char* ws = (char*)d_ws;
    int*            offp   = (int*)(ws + 0);                   // (N+1)*4
    int*            deg    = (int*)(ws + 262144);              // N*4
    int*            cursor = (int*)(ws + 524288);              // N*4
    int*            bsum   = (int*)(ws + 724992);              // NB*4 (inside memset range)
    int*            srcs   = (int*)(ws + 786432);              // E*4
    __hip_bfloat16* W1c    = (__hip_bfloat16*)(ws + 3986432);  // 256*256*2
    __hip_bfloat16* W2c    = (__hip_bfloat16*)(ws + 4117504);  // 256*512*2
    __hip_bfloat16* sb     = (__hip_bfloat16*)(ws + 4379648);  // 8KB
    __hip_bfloat16* xn     = (__hip_bfloat16*)(ws + 4387840);  // N*128*2
    __hip_bfloat16* h1     = (__hip_bfloat16*)(ws + 17187840); // N*256*2
    __hip_bfloat16* agg    = (__hip_bfloat16*)(ws + 42787840); // N*256*2
    int*            flag   = (int*)(ws + 68387840);

    hipMemsetAsync(ws + 262144, 0, 524288, stream);   // zero deg + cursor + bsum

    detect_kernel<<<1, 64, 0, stream>>>((const unsigned short*)x, flag);

    ingest_kernel<<<(N * 128 + 255) / 256, 256, 0, stream>>>(x, xn, N * 128, flag);
    prep_kernel<<<(65536 + 131072 + 2311 + 255) / 256, 256, 0, stream>>>(
        W1l, W1r, W2l, W2r, b1l, b2l, Wh1, Wh2, bh1, bh2, W1c, W2c, sb, flag);

    // CSR build (hierarchical scan)
    deg_kernel<<<(E + 255) / 256, 256, 0, stream>>>(ei, E, deg);
    scanA_kernel<<<NB, 256, 0, stream>>>(deg, offp, bsum, N);
    scanB_kernel<<<1, 1024, 0, stream>>>(bsum, NB);
    addC_kernel<<<(N + 255) / 256, 256, 0, stream>>>(offp, bsum, N);
    fill_kernel<<<(E + 255) / 256, 256, 0, stream>>>(ei, E, offp, cursor, srcs);

    const int rowBlks = (N + 255) / 256;   // 196

    // layer 1 (bf16): h1 = relu([agg1 | xn] @ W1c^T + b1l)
    gather1_kernel<<<(N + 3) / 4, 256, 0, stream>>>(xn, offp, srcs, agg, N);
    gemm_lds<256, 128, true, false><<<rowBlks * 2, 256, 0, stream>>>(
        agg, xn, N, W1c, sb, h1, nullptr, flag);

    // layer 2: h2 -> d_out h-region (flag dtype)
    gather2_kernel<<<(N * 128 + 255) / 256, 256, 0, stream>>>(h1, offp, srcs, agg, N);
    gemm_lds<512, 256, false, true><<<rowBlks * 2, 256, 0, stream>>>(
        agg, h1, N, W2c, sb + 256, nullptr, d_out, flag);

    // heads -> out1/out2 (flag dtype), h2 read from d_out
    heads_kernel<<<(N + 3) / 4, 256, 0, stream>>>(sb, d_out, N, flag);
}

// Round 7
// 390.938 us; speedup vs baseline: 1.8004x; 1.0426x over previous
//
#include <hip/hip_runtime.h>
#include <hip/hip_bf16.h>

typedef short bf16x8 __attribute__((ext_vector_type(8)));   // 8 bf16 bit-patterns (4 VGPRs)
typedef float f32x4 __attribute__((ext_vector_type(4)));

__device__ __forceinline__ float bf2f(__hip_bfloat16 v) { return __bfloat162float(v); }
__device__ __forceinline__ float sh2f(short s) {
    union { float f; unsigned u; } c; c.u = ((unsigned)(unsigned short)s) << 16; return c.f;
}
__device__ __forceinline__ short f2sh(float f) {
    __hip_bfloat16 b = __float2bfloat16(f); return *(short*)&b;
}

// ---------------- dtype detect: flag=1 -> tensors are f32, flag=0 -> bf16
__global__ void detect_kernel(const unsigned short* __restrict__ xu, int* __restrict__ flag) {
    int lane = threadIdx.x;                       // 64 lanes, even u16s 0..126
    unsigned short u = xu[lane * 2];
    unsigned e = (u >> 7) & 0xFF;
    bool good = (u == 0) || (e >= 110 && e <= 137);
    unsigned long long m = __ballot(good);
    if (lane == 0) *flag = (__popcll(m) < 32) ? 1 : 0;
}

__device__ __forceinline__ float loadAny(const void* p, size_t i, int isf32) {
    return isf32 ? ((const float*)p)[i] : bf2f(((const __hip_bfloat16*)p)[i]);
}

// ---------------- normalize x to bf16 (4 elems/thread)
__global__ void ingest_kernel(const void* __restrict__ src, __hip_bfloat16* __restrict__ dst,
                              int n4, const int* __restrict__ flag) {
    int isf32 = *flag;
    int t = blockIdx.x * blockDim.x + threadIdx.x;
    if (t >= n4) return;
    short4 o;
    if (isf32) {
        float4 v = ((const float4*)src)[t];
        o.x = f2sh(v.x); o.y = f2sh(v.y); o.z = f2sh(v.z); o.w = f2sh(v.w);
    } else {
        o = ((const short4*)src)[t];
    }
    ((short4*)dst)[t] = o;
}

// ---------------- weight prep (merged): W1c | W2c | sb
__global__ void prep_kernel(const void* W1l, const void* W1r, const void* W2l, const void* W2r,
                            const void* b1l, const void* b2l, const void* Wh1, const void* Wh2,
                            const void* bh1, const void* bh2,
                            __hip_bfloat16* __restrict__ W1c, __hip_bfloat16* __restrict__ W2c,
                            __hip_bfloat16* __restrict__ sb, const int* __restrict__ flag) {
    int isf32 = *flag;
    int t = blockIdx.x * blockDim.x + threadIdx.x;
    if (t < 65536) {
        int n = t >> 8, k = t & 255;
        float v = (k < 128) ? loadAny(W1l, n * 128 + k, isf32)
                            : loadAny(W1r, n * 128 + (k - 128), isf32);
        W1c[t] = __float2bfloat16(v);
        return;
    }
    int u = t - 65536;
    if (u < 131072) {
        int n = u >> 9, k = u & 511;
        float v = (k < 256) ? loadAny(W2l, n * 256 + k, isf32)
                            : loadAny(W2r, n * 256 + (k - 256), isf32);
        W2c[u] = __float2bfloat16(v);
        return;
    }
    int s = u - 131072;
    float v;
    if      (s < 256)  v = loadAny(b1l, s, isf32);
    else if (s < 512)  v = loadAny(b2l, s - 256, isf32);
    else if (s < 1536) v = loadAny(Wh1, s - 512, isf32);
    else if (s < 2304) v = loadAny(Wh2, s - 1536, isf32);
    else if (s < 2308) v = loadAny(bh1, s - 2304, isf32);
    else if (s < 2311) v = loadAny(bh2, s - 2308, isf32);
    else return;
    sb[s] = __float2bfloat16(v);
}

// ---------------- CSR build
__global__ void deg_kernel(const int* __restrict__ ei, int E, int* __restrict__ deg) {
    int t = blockIdx.x * blockDim.x + threadIdx.x;
    if (t >= E) return;
    atomicAdd(&deg[ei[E + t]], 1);
}

__global__ __launch_bounds__(256) void scanA_kernel(const int* __restrict__ deg,
                                                    int* __restrict__ off,
                                                    int* __restrict__ bsum, int N) {
    __shared__ int ts[256];
    int t = threadIdx.x;
    int base = blockIdx.x * 1024 + t * 4;
    int v0 = (base + 0 < N) ? deg[base + 0] : 0;
    int v1 = (base + 1 < N) ? deg[base + 1] : 0;
    int v2 = (base + 2 < N) ? deg[base + 2] : 0;
    int v3 = (base + 3 < N) ? deg[base + 3] : 0;
    int i0 = v0, i1 = i0 + v1, i2 = i1 + v2, i3 = i2 + v3;
    ts[t] = i3;
    __syncthreads();
    for (int d = 1; d < 256; d <<= 1) {
        int x = (t >= d) ? ts[t - d] : 0;
        __syncthreads();
        ts[t] += x;
        __syncthreads();
    }
    int excl = (t > 0) ? ts[t - 1] : 0;
    if (base + 0 < N) off[base + 1] = excl + i0;
    if (base + 1 < N) off[base + 2] = excl + i1;
    if (base + 2 < N) off[base + 3] = excl + i2;
    if (base + 3 < N) off[base + 4] = excl + i3;
    if (t == 255) bsum[blockIdx.x] = ts[255];
}

__global__ __launch_bounds__(1024) void scanB_kernel(int* __restrict__ bsum, int nb) {
    __shared__ int ts[1024];
    int t = threadIdx.x;
    ts[t] = (t < nb) ? bsum[t] : 0;
    __syncthreads();
    for (int d = 1; d < 1024; d <<= 1) {
        int x = (t >= d) ? ts[t - d] : 0;
        __syncthreads();
        ts[t] += x;
        __syncthreads();
    }
    if (t < nb) bsum[t] = (t > 0) ? ts[t - 1] : 0;
}

__global__ void addC_kernel(int* __restrict__ off, const int* __restrict__ bsum, int N) {
    int i = blockIdx.x * blockDim.x + threadIdx.x;
    if (i == 0) off[0] = 0;
    if (i < N) off[i + 1] += bsum[i >> 10];
}

__global__ void fill_kernel(const int* __restrict__ ei, int E,
                            const int* __restrict__ off, int* __restrict__ cursor,
                            int* __restrict__ srcs) {
    int t = blockIdx.x * blockDim.x + threadIdx.x;
    if (t >= E) return;
    int dst = ei[E + t];
    int pos = off[dst] + atomicAdd(&cursor[dst], 1);
    srcs[pos] = ei[t];
}

// ---------------- gather-mean F=128: 2 nodes/wave (32 lanes x 8B = 256B row), 8-way unroll
__global__ void gather1_kernel(const __hip_bfloat16* __restrict__ x,
                               const int* __restrict__ off, const int* __restrict__ srcs,
                               __hip_bfloat16* __restrict__ agg, int N) {
    int gid  = blockIdx.x * blockDim.x + threadIdx.x;
    int wid  = gid >> 6;
    int lane = threadIdx.x & 63;
    int node = wid * 2 + (lane >> 5);
    int t    = lane & 31;                         // 8B unit within row (32 units)
    if (node >= N) return;
    int beg = off[node], end = off[node + 1];
    float a0 = 0.f, a1 = 0.f, a2 = 0.f, a3 = 0.f;
    const short4* xb = (const short4*)x;
    int e = beg;
    for (; e + 7 < end; e += 8) {
        short4 v[8];
#pragma unroll
        for (int j = 0; j < 8; j++) v[j] = xb[(size_t)srcs[e + j] * 32 + t];
#pragma unroll
        for (int j = 0; j < 8; j++) {
            a0 += sh2f(v[j].x); a1 += sh2f(v[j].y);
            a2 += sh2f(v[j].z); a3 += sh2f(v[j].w);
        }
    }
    for (; e < end; e++) {
        short4 v = xb[(size_t)srcs[e] * 32 + t];
        a0 += sh2f(v.x); a1 += sh2f(v.y); a2 += sh2f(v.z); a3 += sh2f(v.w);
    }
    float inv = 1.0f / fmaxf((float)(end - beg), 1.0f);
    short4 o;
    o.x = f2sh(a0 * inv); o.y = f2sh(a1 * inv);
    o.z = f2sh(a2 * inv); o.w = f2sh(a3 * inv);
    ((short4*)agg)[(size_t)node * 32 + t] = o;
}

// ---------------- gather-mean F=256: 1 wave/node (64 lanes x 8B = 512B row), 8-way unroll
__global__ void gather2_kernel(const __hip_bfloat16* __restrict__ h,
                               const int* __restrict__ off, const int* __restrict__ srcs,
                               __hip_bfloat16* __restrict__ agg, int N) {
    int node = (blockIdx.x * blockDim.x + threadIdx.x) >> 6;
    int lane = threadIdx.x & 63;                  // 8B unit within row (64 units)
    if (node >= N) return;
    int beg = off[node], end = off[node + 1];
    float a0 = 0.f, a1 = 0.f, a2 = 0.f, a3 = 0.f;
    const short4* hb = (const short4*)h;
    int e = beg;
    for (; e + 7 < end; e += 8) {
        short4 v[8];
#pragma unroll
        for (int j = 0; j < 8; j++) v[j] = hb[(size_t)srcs[e + j] * 64 + lane];
#pragma unroll
        for (int j = 0; j < 8; j++) {
            a0 += sh2f(v[j].x); a1 += sh2f(v[j].y);
            a2 += sh2f(v[j].z); a3 += sh2f(v[j].w);
        }
    }
    for (; e < end; e++) {
        short4 v = hb[(size_t)srcs[e] * 64 + lane];
        a0 += sh2f(v.x); a1 += sh2f(v.y); a2 += sh2f(v.z); a3 += sh2f(v.w);
    }
    float inv = 1.0f / fmaxf((float)(end - beg), 1.0f);
    short4 o;
    o.x = f2sh(a0 * inv); o.y = f2sh(a1 * inv);
    o.z = f2sh(a2 * inv); o.w = f2sh(a3 * inv);
    ((short4*)agg)[(size_t)node * 64 + lane] = o;
}

// ---------------- LDS-staged GEMM, software-pipelined (W chunk prefetch + depth-2 A prefetch)
struct AFrag { bf16x8 v[4]; };

template <int K, int KA, bool RELU, bool TOOUT>
__global__ __launch_bounds__(256) void gemm_lds(const __hip_bfloat16* __restrict__ A1,
                                                const __hip_bfloat16* __restrict__ A2, int M,
                                                const __hip_bfloat16* __restrict__ W,
                                                const __hip_bfloat16* __restrict__ bias,
                                                __hip_bfloat16* __restrict__ outb,
                                                void* __restrict__ dout,
                                                const int* __restrict__ flag) {
    __shared__ short wlds[32768];                 // 64 KB: one 128x256 W chunk, frag-order
    constexpr int KB = K - KA;
    constexpr int NCHUNK = K / 256;
    int tid  = threadIdx.x;
    int wave = tid >> 6, lane = tid & 63, quad = lane >> 4, l15 = lane & 15;
    int rowBlk = blockIdx.x >> 1, half = blockIdx.x & 1;
    int R0 = rowBlk * 256;
    int cbase = half * 128;

    int mrow[4];
#pragma unroll
    for (int rt = 0; rt < 4; rt++) mrow[rt] = min(R0 + wave * 64 + rt * 16 + l15, M - 1);

    const short* Ws = (const short*)W;

    auto loadW = [&](int p, bf16x8* wreg) {
#pragma unroll
        for (int i = 0; i < 16; i++) {
            int unit = tid + i * 256;
            int ln = unit & 63, nt = (unit >> 6) & 7, kt = unit >> 9;
            int row = cbase + nt * 16 + (ln & 15);
            int kk  = p * 256 + kt * 32 + (ln >> 4) * 8;
            wreg[i] = *(const bf16x8*)(Ws + (size_t)row * K + kk);
        }
    };
    auto storeW = [&](const bf16x8* wreg) {
#pragma unroll
        for (int i = 0; i < 16; i++) {
            int unit = tid + i * 256;
            *(bf16x8*)&wlds[unit * 8] = wreg[i];
        }
    };
    auto loadA = [&](int kglob) {
        AFrag f;
#pragma unroll
        for (int rt = 0; rt < 4; rt++) {
            const short* ap = (kglob < KA)
                ? (const short*)A1 + (size_t)mrow[rt] * KA + kglob + quad * 8
                : (const short*)A2 + (size_t)mrow[rt] * KB + (kglob - KA) + quad * 8;
            f.v[rt] = *(const bf16x8*)ap;
        }
        return f;
    };

    f32x4 acc[4][8];
#pragma unroll
    for (int rt = 0; rt < 4; rt++)
#pragma unroll
        for (int nt = 0; nt < 8; nt++) acc[rt][nt] = {0.f, 0.f, 0.f, 0.f};

    bf16x8 wreg[16];
    loadW(0, wreg);
    storeW(wreg);
    __syncthreads();
    AFrag a0f = loadA(0);
    AFrag a1f = loadA(32 < K ? 32 : 0);

    for (int p = 0; p < NCHUNK; p++) {
        if (p + 1 < NCHUNK) loadW(p + 1, wreg);   // global->reg prefetch, no LDS hazard
#pragma unroll
        for (int kt = 0; kt < 8; kt++) {
            int kg = p * 256 + kt * 32;
            int kg2 = kg + 64;                    // depth-2 prefetch target
            if (kg2 > K - 32) kg2 = K - 32;       // clamp (tail: dummy reload, valid addr)
            AFrag a_next = loadA(kg2);
#pragma unroll
            for (int nt = 0; nt < 8; nt++) {
                bf16x8 b = *(const bf16x8*)&wlds[((kt * 8 + nt) * 64 + lane) * 8];
#pragma unroll
                for (int rt = 0; rt < 4; rt++)
                    acc[rt][nt] = __builtin_amdgcn_mfma_f32_16x16x32_bf16(a0f.v[rt], b, acc[rt][nt], 0, 0, 0);
            }
            a0f = a1f;
            a1f = a_next;
        }
        if (p + 1 < NCHUNK) {
            __syncthreads();          // all waves done reading chunk p
            storeW(wreg);
            __syncthreads();
        }
    }

    int isf32 = TOOUT ? *flag : 0;
    float* hf = TOOUT ? ((float*)dout + (size_t)M * 7) : nullptr;
    __hip_bfloat16* hb = TOOUT ? ((__hip_bfloat16*)dout + (size_t)M * 7) : outb;

#pragma unroll
    for (int rt = 0; rt < 4; rt++) {
#pragma unroll
        for (int nt = 0; nt < 8; nt++) {
            int col = cbase + nt * 16 + l15;
            float bv = bf2f(bias[col]);
#pragma unroll
            for (int r = 0; r < 4; r++) {
                int row = R0 + wave * 64 + rt * 16 + quad * 4 + r;
                if (row < M) {
                    float v = acc[rt][nt][r] + bv;
                    if (RELU) v = fmaxf(v, 0.f);
                    size_t idx = (size_t)row * 256 + col;
                    if (TOOUT && isf32) hf[idx] = v;
                    else                hb[idx] = __float2bfloat16(v);
                }
            }
        }
    }
}

// ---------------- heads: out1[N,4] @ d_out+0, out2[N,3] @ d_out+N*4; h2 from d_out (flag dtype)
__global__ void heads_kernel(const __hip_bfloat16* __restrict__ sb,
                             void* dout, int N, const int* __restrict__ flag) {
    int isf32 = *flag;
    int node = (blockIdx.x * blockDim.x + threadIdx.x) >> 6;
    int lane = threadIdx.x & 63;
    if (node >= N) return;
    float hv0, hv1, hv2, hv3;
    if (isf32) {
        const float4* hp = (const float4*)((const float*)dout + (size_t)N * 7);
        float4 v = hp[(size_t)node * 64 + lane];
        hv0 = v.x; hv1 = v.y; hv2 = v.z; hv3 = v.w;
    } else {
        const __hip_bfloat162* hp = (const __hip_bfloat162*)((const __hip_bfloat16*)dout + (size_t)N * 7);
        __hip_bfloat162 a = hp[(size_t)node * 128 + 2 * lane];
        __hip_bfloat162 b = hp[(size_t)node * 128 + 2 * lane + 1];
        hv0 = bf2f(a.x); hv1 = bf2f(a.y); hv2 = bf2f(b.x); hv3 = bf2f(b.y);
    }
#pragma unroll
    for (int r = 0; r < 7; r++) {
        const __hip_bfloat16* wrow = (r < 4) ? (sb + 512 + r * 256) : (sb + 1536 + (r - 4) * 256);
        const __hip_bfloat162* wr2 = (const __hip_bfloat162*)wrow;
        __hip_bfloat162 wa = wr2[2 * lane];
        __hip_bfloat162 wb = wr2[2 * lane + 1];
        float p = hv0 * bf2f(wa.x) + hv1 * bf2f(wa.y) + hv2 * bf2f(wb.x) + hv3 * bf2f(wb.y);
        for (int off = 32; off > 0; off >>= 1) p += __shfl_down(p, off, 64);
        if (lane == 0) {
            float bias = (r < 4) ? bf2f(sb[2304 + r]) : bf2f(sb[2308 + (r - 4)]);
            float v = p + bias;
            size_t idx = (r < 4) ? ((size_t)node * 4 + r)
                                 : ((size_t)N * 4 + (size_t)node * 3 + (r - 4));
            if (isf32) ((float*)dout)[idx] = v;
            else       ((__hip_bfloat16*)dout)[idx] = __float2bfloat16(v);
        }
    }
}

extern "C" void kernel_launch(void* const* d_in, const int* in_sizes, int n_in,
                              void* d_out, int out_size, void* d_ws, size_t ws_size,
                              hipStream_t stream) {
    const void* x   = d_in[0];
    const int*  ei  = (const int*)d_in[1];
    const void* W1l = d_in[2];
    const void* b1l = d_in[3];
    const void* W1r = d_in[4];
    const void* W2l = d_in[5];
    const void* b2l = d_in[6];
    const void* W2r = d_in[7];
    const void* Wh1 = d_in[8];
    const void* bh1 = d_in[9];
    const void* Wh2 = d_in[10];
    const void* bh2 = d_in[11];

    const int N = in_sizes[0] / 128;   // 50000
    const int E = in_sizes[1] / 2;     // 800000
    const int NB = (N + 1023) / 1024;  // scan blocks (49)

    // workspace layout (bytes), total ~68.4 MB, 64B-aligned
    char* ws = (char*)d_ws;
    int*            offp   = (int*)(ws + 0);                   // (N+1)*4
    int*            deg    = (int*)(ws + 262144);              // N*4
    int*            cursor = (int*)(ws + 524288);              // N*4
    int*            bsum   = (int*)(ws + 724992);              // NB*4 (inside memset range)
    int*            srcs   = (int*)(ws + 786432);              // E*4
    __hip_bfloat16* W1c    = (__hip_bfloat16*)(ws + 3986432);  // 256*256*2
    __hip_bfloat16* W2c    = (__hip_bfloat16*)(ws + 4117504);  // 256*512*2
    __hip_bfloat16* sb     = (__hip_bfloat16*)(ws + 4379648);  // 8KB
    __hip_bfloat16* xn     = (__hip_bfloat16*)(ws + 4387840);  // N*128*2
    __hip_bfloat16* h1     = (__hip_bfloat16*)(ws + 17187840); // N*256*2
    __hip_bfloat16* agg    = (__hip_bfloat16*)(ws + 42787840); // N*256*2
    int*            flag   = (int*)(ws + 68387840);

    hipMemsetAsync(ws + 262144, 0, 524288, stream);   // zero deg + cursor + bsum

    detect_kernel<<<1, 64, 0, stream>>>((const unsigned short*)x, flag);

    ingest_kernel<<<(N * 32 + 255) / 256, 256, 0, stream>>>(x, xn, N * 32, flag);
    prep_kernel<<<(65536 + 131072 + 2311 + 255) / 256, 256, 0, stream>>>(
        W1l, W1r, W2l, W2r, b1l, b2l, Wh1, Wh2, bh1, bh2, W1c, W2c, sb, flag);

    // CSR build (hierarchical scan)
    deg_kernel<<<(E + 255) / 256, 256, 0, stream>>>(ei, E, deg);
    scanA_kernel<<<NB, 256, 0, stream>>>(deg, offp, bsum, N);
    scanB_kernel<<<1, 1024, 0, stream>>>(bsum, NB);
    addC_kernel<<<(N + 255) / 256, 256, 0, stream>>>(offp, bsum, N);
    fill_kernel<<<(E + 255) / 256, 256, 0, stream>>>(ei, E, offp, cursor, srcs);

    const int rowBlks = (N + 255) / 256;   // 196

    // layer 1 (bf16): h1 = relu([agg1 | xn] @ W1c^T + b1l)
    {
        int waves = (N + 1) / 2;
        gather1_kernel<<<(waves * 64 + 255) / 256, 256, 0, stream>>>(xn, offp, srcs, agg, N);
    }
    gemm_lds<256, 128, true, false><<<rowBlks * 2, 256, 0, stream>>>(
        agg, xn, N, W1c, sb, h1, nullptr, flag);

    // layer 2: h2 -> d_out h-region (flag dtype)
    gather2_kernel<<<(N * 64 + 255) / 256, 256, 0, stream>>>(h1, offp, srcs, agg, N);
    gemm_lds<512, 256, false, true><<<rowBlks * 2, 256, 0, stream>>>(
        agg, h1, N, W2c, sb + 256, nullptr, d_out, flag);

    // heads -> out1/out2 (flag dtype), h2 read from d_out
    heads_kernel<<<(N + 3) / 4, 256, 0, stream>>>(sb, d_out, N, flag);
}